// Round 8
// baseline (1324.762 us; speedup 1.0000x reference)
//
#include <hip/hip_runtime.h>
#include <hip/hip_bf16.h>
#include <stdint.h>

#define BETA 0.5f
#define IGNORE_INDEX (-100)

typedef short bf16x8 __attribute__((ext_vector_type(8)));
typedef float f32x4 __attribute__((ext_vector_type(4)));

// ---------------------------------------------------------------- converts
// Activations only (48 MB fp32) -- weights are converted inside the GEMM.
__global__ __launch_bounds__(256) void f32_to_bf16_kernel(
    const float* __restrict__ in, uint16_t* __restrict__ out, int n) {
  int i = (blockIdx.x * blockDim.x + threadIdx.x) * 4;
  const int stride = gridDim.x * blockDim.x * 4;
  for (; i < n; i += stride) {
    float4 v = *reinterpret_cast<const float4*>(in + i);
    __hip_bfloat16 b0 = __float2bfloat16(v.x);
    __hip_bfloat16 b1 = __float2bfloat16(v.y);
    __hip_bfloat16 b2 = __float2bfloat16(v.z);
    __hip_bfloat16 b3 = __float2bfloat16(v.w);
    ushort4 o;
    o.x = *reinterpret_cast<const uint16_t*>(&b0);
    o.y = *reinterpret_cast<const uint16_t*>(&b1);
    o.z = *reinterpret_cast<const uint16_t*>(&b2);
    o.w = *reinterpret_cast<const uint16_t*>(&b3);
    *reinterpret_cast<ushort4*>(out + i) = o;
  }
}

// ---------------------------------------------------------------- GEMM (NT)
// C[n][v] = sum_k A[n][k]*B[v][k].  A: bf16 [M][K] (pre-converted
// activations); B: fp32 [V][K] (weights, converted IN-KERNEL during
// staging -- saves the 786 MB W convert round-trip).  256x256 tile, BK=64,
// 8 waves (2Mx4N), barrier-free tile body (r7), conflict-free granule XOR
// layout.  B staging: reg-stage fp32 -> cvt_pk bf16 -> ds_write_b128 into
// buf[(T+1)&1] (readers retired before previous boundary barrier =>
// race-free, unlike r7's same-buffer gload_lds).  T14 split: h0 loads @c1
// -> write @c3; h1 loads @c3 -> write @c4 (peak +16 VGPR).  Compiler
// auto-inserts counted vmcnt for the reg loads.  Boundary: vmcnt(0)
// (drains 4 old A-gload_lds, free) + lgkmcnt(0) (ds_write visibility) +
// barrier.  setprio (T5), XCD swizzle (T1).
// LDS: 2 buf x (A 32K + B 32K) = 128 KiB.
// Merged launch: blocks [0,half) = teacher, [half,2*half) = student.

__global__ __launch_bounds__(512, 2) void gemm_fz_kernel(
    const uint16_t* __restrict__ At, const float* __restrict__ Bt,
    uint16_t* __restrict__ Ct, int Kt,
    const uint16_t* __restrict__ As_, const float* __restrict__ Bs_,
    uint16_t* __restrict__ Cs, int Ks,
    int V, int RT, int CT) {
  __shared__ __align__(16) uint16_t lds[65536];

  const int half = RT * CT;
  const uint16_t* A;
  const float* B;
  uint16_t* C;
  int K, bidx = blockIdx.x;
  if (bidx < half) { A = At; B = Bt; C = Ct; K = Kt; }
  else             { A = As_; B = Bs_; C = Cs; K = Ks; bidx -= half; }

  int L = ((half & 7) == 0) ? ((bidx & 7) * (half >> 3) + (bidx >> 3)) : bidx;
  const int rt = L % RT;
  const int ct = L / RT;
  const int row0 = rt * 256;
  const int col0 = ct * 256;

  const int i  = threadIdx.x;      // 0..511
  const int w  = i >> 6;
  const int l  = i & 63;
  const int wl = l & 15;
  const int kg = l >> 4;
  const int wr = w >> 2;           // wave row 0..1 (128 out rows)
  const int wc = w & 3;            // wave col 0..3 (64 out cols)

  const int nT = K >> 6;           // BK = 64

  // ---- A staging (gload_lds, bf16): thread i -> granules i, i+512 per half.
  const int r0 = i >> 3;
  const int clog = (i & 7) ^ (r0 & 7);
  const uint16_t* aSrc = A + (size_t)(row0 + r0) * K + clog * 8;
  uint16_t* ldsu = lds;

#define GL(srcp, dstp)                                                     \
  __builtin_amdgcn_global_load_lds(                                        \
      (const __attribute__((address_space(1))) void*)(srcp),               \
      (__attribute__((address_space(3))) void*)(dstp), 16, 0, 0)

#define STAGE_A(TT, HH)                                                    \
  do {                                                                     \
    const uint16_t* _s = aSrc + (size_t)(HH) * 128 * K + (size_t)(TT) * 64;\
    uint16_t* _d = ldsu + (((TT) & 1) * 32768) + (HH) * 8192 + i * 8;      \
    GL(_s, _d); GL(_s + (size_t)64 * K, _d + 4096);                        \
  } while (0)

  // ---- B staging (fp32 -> bf16 in-kernel): thread i -> row r4 = i>>2 of
  // the half, cols [qq*16, qq*16+16).  Two granules (r4, ph0/ph1).
  const int r4 = i >> 2;           // 0..127
  const int qq = i & 3;
  const int ph0 = (qq * 2)     ^ (r4 & 7);
  const int ph1 = (qq * 2 + 1) ^ (r4 & 7);
  const float* bF = B + (size_t)(col0 + r4) * K + qq * 16;

#define BLOAD(TT, HH, V0, V1, V2, V3)                                      \
  do {                                                                     \
    const float4* _p = reinterpret_cast<const float4*>(                    \
        bF + (size_t)(HH) * 128 * K + (size_t)(TT) * 64);                  \
    V0 = _p[0]; V1 = _p[1]; V2 = _p[2]; V3 = _p[3];                        \
  } while (0)

  auto cv = [](float x) -> uint32_t {
    __hip_bfloat16 h = __float2bfloat16(x);
    return (uint32_t)*reinterpret_cast<const uint16_t*>(&h);
  };
  auto packg = [&cv](const float4& a, const float4& b) -> uint4 {
    uint4 u;
    u.x = cv(a.x) | (cv(a.y) << 16);
    u.y = cv(a.z) | (cv(a.w) << 16);
    u.z = cv(b.x) | (cv(b.y) << 16);
    u.w = cv(b.z) | (cv(b.w) << 16);
    return u;
  };

#define BWRITE(TT, HH, V0, V1, V2, V3)                                     \
  do {                                                                     \
    uint16_t* _w = ldsu + (((TT) & 1) * 32768 + 16384 + (HH) * 8192);      \
    *reinterpret_cast<uint4*>(_w + (r4 * 8 + ph0) * 8) = packg(V0, V1);    \
    *reinterpret_cast<uint4*>(_w + (r4 * 8 + ph1) * 8) = packg(V2, V3);    \
  } while (0)

  // ---- ds_read byte offsets (A-half = wr; B-half = wc>>1).
  // phys col = (slot*4+kg) ^ (wl&7).
  int offA[8][2], offB[4][2];
#pragma unroll
  for (int m = 0; m < 8; ++m) {
    const int rho = (m & 3) * 16 + wl;
    const int mh = m >> 2;
#pragma unroll
    for (int s = 0; s < 2; ++s)
      offA[m][s] = wr * 16384 + mh * 8192 + rho * 128 +
                   (((s * 4 + kg) ^ (wl & 7)) * 16);
  }
#pragma unroll
  for (int n = 0; n < 4; ++n) {
    const int sig = (wc & 1) * 64 + n * 16 + wl;
#pragma unroll
    for (int s = 0; s < 2; ++s)
      offB[n][s] = 32768 + (wc >> 1) * 16384 + sig * 128 +
                   (((s * 4 + kg) ^ (wl & 7)) * 16);
  }

  f32x4 acc[8][4] = {};
  bf16x8 af[4], bf[4], ag[4];

  // ---- prologue: stage A(0) + B(0) (sequential halves, low reg pressure)
  STAGE_A(0, 0); STAGE_A(0, 1);
  {
    float4 x0, x1, x2, x3;
    BLOAD(0, 0, x0, x1, x2, x3); BWRITE(0, 0, x0, x1, x2, x3);
    BLOAD(0, 1, x0, x1, x2, x3); BWRITE(0, 1, x0, x1, x2, x3);
  }
  asm volatile("s_waitcnt vmcnt(0)" ::: "memory");
  asm volatile("s_waitcnt lgkmcnt(0)" ::: "memory");
  __builtin_amdgcn_s_barrier();
  __builtin_amdgcn_sched_barrier(0);

  for (int T = 0; T < nT; ++T) {
    const char* bb = (const char*)lds + (T & 1) * 65536;
    const bool stg1 = (T + 1) < nT;
    float4 x0, x1, x2, x3;

    // ---------- chunk 1: read A(mh0,s0)+B(s0); issue B(T+1)h0 loads;
    //                     stage A(T+1,0); MFMA m0..3 s0
#pragma unroll
    for (int m = 0; m < 4; ++m)
      af[m] = *reinterpret_cast<const bf16x8*>(bb + offA[m][0]);
#pragma unroll
    for (int n = 0; n < 4; ++n)
      bf[n] = *reinterpret_cast<const bf16x8*>(bb + offB[n][0]);
    if (stg1) { BLOAD(T + 1, 0, x0, x1, x2, x3); STAGE_A(T + 1, 0); }
    __builtin_amdgcn_s_setprio(1);
#pragma unroll
    for (int m = 0; m < 4; ++m)
#pragma unroll
      for (int n = 0; n < 4; ++n)
        acc[m][n] = __builtin_amdgcn_mfma_f32_16x16x32_bf16(
            af[m], bf[n], acc[m][n], 0, 0, 0);
    __builtin_amdgcn_s_setprio(0);

    // ---------- chunk 2: read A(mh1,s0); stage A(T+1,1); MFMA m4..7 s0
#pragma unroll
    for (int m = 0; m < 4; ++m)
      ag[m] = *reinterpret_cast<const bf16x8*>(bb + offA[4 + m][0]);
    if (stg1) STAGE_A(T + 1, 1);
    __builtin_amdgcn_s_setprio(1);
#pragma unroll
    for (int m = 0; m < 4; ++m)
#pragma unroll
      for (int n = 0; n < 4; ++n)
        acc[4 + m][n] = __builtin_amdgcn_mfma_f32_16x16x32_bf16(
            ag[m], bf[n], acc[4 + m][n], 0, 0, 0);
    __builtin_amdgcn_s_setprio(0);

    // ---------- chunk 3: read A(mh0,s1)+B(s1); write B(T+1)h0 (cvt, auto
    //                     vmcnt); issue B(T+1)h1 loads; MFMA m0..3 s1
#pragma unroll
    for (int m = 0; m < 4; ++m)
      af[m] = *reinterpret_cast<const bf16x8*>(bb + offA[m][1]);
#pragma unroll
    for (int n = 0; n < 4; ++n)
      bf[n] = *reinterpret_cast<const bf16x8*>(bb + offB[n][1]);
    float4 y0, y1, y2, y3;
    if (stg1) {
      BWRITE(T + 1, 0, x0, x1, x2, x3);
      BLOAD(T + 1, 1, y0, y1, y2, y3);
    }
    __builtin_amdgcn_s_setprio(1);
#pragma unroll
    for (int m = 0; m < 4; ++m)
#pragma unroll
      for (int n = 0; n < 4; ++n)
        acc[m][n] = __builtin_amdgcn_mfma_f32_16x16x32_bf16(
            af[m], bf[n], acc[m][n], 0, 0, 0);
    __builtin_amdgcn_s_setprio(0);

    // ---------- chunk 4: read A(mh1,s1); write B(T+1)h1; MFMA m4..7 s1
#pragma unroll
    for (int m = 0; m < 4; ++m)
      ag[m] = *reinterpret_cast<const bf16x8*>(bb + offA[4 + m][1]);
    if (stg1) BWRITE(T + 1, 1, y0, y1, y2, y3);
    __builtin_amdgcn_s_setprio(1);
#pragma unroll
    for (int m = 0; m < 4; ++m)
#pragma unroll
      for (int n = 0; n < 4; ++n)
        acc[4 + m][n] = __builtin_amdgcn_mfma_f32_16x16x32_bf16(
            ag[m], bf[n], acc[4 + m][n], 0, 0, 0);
    __builtin_amdgcn_s_setprio(0);

    // ---------- boundary: drain A-gload_lds (old, free) + ds_writes; barrier
    asm volatile("s_waitcnt vmcnt(0)" ::: "memory");
    asm volatile("s_waitcnt lgkmcnt(0)" ::: "memory");
    __builtin_amdgcn_s_barrier();
    __builtin_amdgcn_sched_barrier(0);
  }

  // ---- epilogue: C/D layout col=lane&15, row=(lane>>4)*4+reg
#pragma unroll
  for (int mg = 0; mg < 8; ++mg)
#pragma unroll
    for (int ng = 0; ng < 4; ++ng)
#pragma unroll
      for (int r = 0; r < 4; ++r) {
        const int row = row0 + wr * 128 + mg * 16 + kg * 4 + r;
        const int col = col0 + wc * 64 + ng * 16 + wl;
        __hip_bfloat16 bv = __float2bfloat16(acc[mg][ng][r]);
        C[(size_t)row * V + col] = *reinterpret_cast<const uint16_t*>(&bv);
      }
#undef STAGE_A
#undef BLOAD
#undef BWRITE
#undef GL
}

// ---------------------------------------------------------------- JSD rows
__device__ __forceinline__ void unpack8(uint4 v, float* f) {
  uint32_t w[4] = {v.x, v.y, v.z, v.w};
#pragma unroll
  for (int j = 0; j < 4; ++j) {
    union { uint32_t u; float x; } lo, hi;
    lo.u = (w[j] & 0xffffu) << 16;
    hi.u = w[j] & 0xffff0000u;
    f[2 * j] = lo.x;
    f[2 * j + 1] = hi.x;
  }
}

__device__ __forceinline__ float blockReduce(float v, bool isMax, float* sh) {
#pragma unroll
  for (int o = 32; o >= 1; o >>= 1) {
    float other = __shfl_xor(v, o, 64);
    v = isMax ? fmaxf(v, other) : (v + other);
  }
  const int w = threadIdx.x >> 6;
  __syncthreads();
  if ((threadIdx.x & 63) == 0) sh[w] = v;
  __syncthreads();
  float r = sh[0];
#pragma unroll
  for (int i = 1; i < 4; ++i) r = isMax ? fmaxf(r, sh[i]) : (r + sh[i]);
  return r;
}

__global__ __launch_bounds__(256) void jsd_rows_kernel(
    const uint16_t* __restrict__ SL, const uint16_t* __restrict__ TL,
    float* __restrict__ per_tok, int V) {
  __shared__ __align__(16) uint16_t rowS[32000];
  __shared__ __align__(16) uint16_t rowT[32000];
  __shared__ float red[4];

  const int t = threadIdx.x;
  const int row = blockIdx.x;
  const uint4* gS = reinterpret_cast<const uint4*>(SL + (size_t)row * V);
  const uint4* gT = reinterpret_cast<const uint4*>(TL + (size_t)row * V);
  uint4* lS = reinterpret_cast<uint4*>(rowS);
  uint4* lT = reinterpret_cast<uint4*>(rowT);
  const int nvec = V >> 3;  // 4000

  for (int i = t; i < nvec; i += 256) { lS[i] = gS[i]; lT[i] = gT[i]; }
  __syncthreads();

  float mS = -3.0e38f, mT = -3.0e38f;
  for (int i = t; i < nvec; i += 256) {
    float fs[8], ft[8];
    unpack8(lS[i], fs);
    unpack8(lT[i], ft);
#pragma unroll
    for (int j = 0; j < 8; ++j) { mS = fmaxf(mS, fs[j]); mT = fmaxf(mT, ft[j]); }
  }
  mS = blockReduce(mS, true, red);
  mT = blockReduce(mT, true, red);

  float sS = 0.f, sT = 0.f;
  for (int i = t; i < nvec; i += 256) {
    float fs[8], ft[8];
    unpack8(lS[i], fs);
    unpack8(lT[i], ft);
#pragma unroll
    for (int j = 0; j < 8; ++j) { sS += __expf(fs[j] - mS); sT += __expf(ft[j] - mT); }
  }
  sS = blockReduce(sS, false, red);
  sT = blockReduce(sT, false, red);
  const float lseS = mS + __logf(sS);
  const float lseT = mT + __logf(sT);

  float acc = 0.f;
  for (int i = t; i < nvec; i += 256) {
    float fs[8], ft[8];
    unpack8(lS[i], fs);
    unpack8(lT[i], ft);
#pragma unroll
    for (int j = 0; j < 8; ++j) {
      const float lq = fs[j] - lseS;
      const float lp = ft[j] - lseT;
      const float q = __expf(lq);
      const float p = __expf(lp);
      const float m = BETA * p + (1.f - BETA) * q;
      const float lm = __logf(m);
      acc += BETA * p * (lp - lm) + (1.f - BETA) * q * (lq - lm);
    }
  }
  acc = blockReduce(acc, false, red);
  if (t == 0) per_tok[row] = acc;
}

// ---------------------------------------------------------------- finalize
__global__ __launch_bounds__(256) void finalize_kernel(
    const float* __restrict__ per_tok, const int* __restrict__ tgt,
    float* __restrict__ out, int N) {
  __shared__ float redf[4];
  __shared__ int redi[4];
  float s = 0.f;
  int c = 0;
  for (int i = threadIdx.x; i < N; i += 256) {
    if (tgt[i] != IGNORE_INDEX) { s += per_tok[i]; c += 1; }
  }
#pragma unroll
  for (int o = 32; o >= 1; o >>= 1) {
    s += __shfl_xor(s, o, 64);
    c += __shfl_xor(c, o, 64);
  }
  const int w = threadIdx.x >> 6;
  if ((threadIdx.x & 63) == 0) { redf[w] = s; redi[w] = c; }
  __syncthreads();
  if (threadIdx.x == 0) {
    float st = 0.f;
    int ct = 0;
#pragma unroll
    for (int i = 0; i < 4; ++i) { st += redf[i]; ct += redi[i]; }
    out[0] = st / (float)(ct > 0 ? ct : 1);
  }
}

// ---------------------------------------------------------------- launch
extern "C" void kernel_launch(void* const* d_in, const int* in_sizes, int n_in,
                              void* d_out, int out_size, void* d_ws, size_t ws_size,
                              hipStream_t stream) {
  const float* student = (const float*)d_in[0];
  const float* W_s     = (const float*)d_in[1];
  const float* teacher = (const float*)d_in[2];
  const float* W_t     = (const float*)d_in[3];
  const int*   target  = (const int*)d_in[4];

  const int N  = in_sizes[4];            // 2048
  const int Hs = in_sizes[0] / N;        // 2048
  const int Ht = in_sizes[2] / N;        // 4096
  const int V  = in_sizes[1] / Hs;       // 32000

  char* ws = (char*)d_ws;
  size_t off = 0;
  auto alloc = [&](size_t bytes) -> void* {
    void* p = ws + off;
    off += (bytes + 255) & ~(size_t)255;
    return p;
  };
  uint16_t* Sbf  = (uint16_t*)alloc((size_t)N * Hs * 2);
  uint16_t* Tbf  = (uint16_t*)alloc((size_t)N * Ht * 2);
  uint16_t* slog = (uint16_t*)alloc((size_t)N * V * 2);
  uint16_t* tlog = (uint16_t*)alloc((size_t)N * V * 2);
  float* per_tok = (float*)alloc((size_t)N * sizeof(float));
  (void)ws_size;  // total ~287 MB

  // activations only (weights converted inside the GEMM)
  f32_to_bf16_kernel<<<1024, 256, 0, stream>>>(student, Sbf, N * Hs);
  f32_to_bf16_kernel<<<1024, 256, 0, stream>>>(teacher, Tbf, N * Ht);

  const int RT = N / 256;   // 8
  const int CT = V / 256;   // 125
  // merged launch: teacher blocks first, student backfills the tail
  gemm_fz_kernel<<<2 * RT * CT, 512, 0, stream>>>(
      Tbf, W_t, tlog, Ht, Sbf, W_s, slog, Hs, V, RT, CT);

  jsd_rows_kernel<<<N, 256, 0, stream>>>(slog, tlog, per_tok, V);
  finalize_kernel<<<1, 256, 0, stream>>>(per_tok, target, (float*)d_out, N);
}

// Round 9
// 1127.682 us; speedup vs baseline: 1.1748x; 1.1748x over previous
//
#include <hip/hip_runtime.h>
#include <hip/hip_bf16.h>
#include <stdint.h>

#define BETA 0.5f
#define IGNORE_INDEX (-100)

typedef short bf16x8 __attribute__((ext_vector_type(8)));
typedef float f32x4 __attribute__((ext_vector_type(4)));
typedef float f32x16 __attribute__((ext_vector_type(16)));

// ---------------------------------------------------------------- converts
__global__ __launch_bounds__(256) void f32_to_bf16_kernel(
    const float* __restrict__ in, uint16_t* __restrict__ out, int n) {
  int i = (blockIdx.x * blockDim.x + threadIdx.x) * 4;
  const int stride = gridDim.x * blockDim.x * 4;
  for (; i < n; i += stride) {
    float4 v = *reinterpret_cast<const float4*>(in + i);
    __hip_bfloat16 b0 = __float2bfloat16(v.x);
    __hip_bfloat16 b1 = __float2bfloat16(v.y);
    __hip_bfloat16 b2 = __float2bfloat16(v.z);
    __hip_bfloat16 b3 = __float2bfloat16(v.w);
    ushort4 o;
    o.x = *reinterpret_cast<const uint16_t*>(&b0);
    o.y = *reinterpret_cast<const uint16_t*>(&b1);
    o.z = *reinterpret_cast<const uint16_t*>(&b2);
    o.w = *reinterpret_cast<const uint16_t*>(&b3);
    *reinterpret_cast<ushort4*>(out + i) = o;
  }
}

// ---------------------------------------------------------------- GEMM (NT)
// C[n][v] = sum_k A[n][k]*B[v][k].  256x256 tile, BK=64, 8 waves (2Mx4N).
// r7 schedule EXACTLY (barrier-free tile body, one boundary barrier,
// A(T+1)@c1/c2 -> other buffer, B(T+2)@c4 -> current buffer, counted
// vmcnt(4)), with 32x32x16 MFMA fragments: MFMA floor 2368->2067 cyc/tile
// (m119: 2495 vs 2176 TF) and half the MFMA instruction count.  LDS read
// count unchanged (24 b128/wave/tile); same XOR-granule layout (0 conflicts
// in r7).  A/B frag: row/col = lane&31, k-half = lane>>5 (8 bf16/lane).
// C/D: col = lane&31, row = (r&3)+8*(r>>2)+4*(lane>>5)  [m74/m101].
// LDS: 2 buf x (A 32K + B 32K) = 128 KiB.
// Merged launch: blocks [0,half) = teacher, [half,2*half) = student.

__global__ __launch_bounds__(512, 2) void gemm32_kernel(
    const uint16_t* __restrict__ At, const uint16_t* __restrict__ Bt,
    uint16_t* __restrict__ Ct, int Kt,
    const uint16_t* __restrict__ As_, const uint16_t* __restrict__ Bs_,
    uint16_t* __restrict__ Cs, int Ks,
    int V, int RT, int CT) {
  __shared__ __align__(16) uint16_t lds[65536];

  const int half = RT * CT;
  const uint16_t *A, *B;
  uint16_t* C;
  int K, bidx = blockIdx.x;
  if (bidx < half) { A = At; B = Bt; C = Ct; K = Kt; }
  else             { A = As_; B = Bs_; C = Cs; K = Ks; bidx -= half; }

  int L = ((half & 7) == 0) ? ((bidx & 7) * (half >> 3) + (bidx >> 3)) : bidx;
  const int rt = L % RT;
  const int ct = L / RT;
  const int row0 = rt * 256;
  const int col0 = ct * 256;

  const int i  = threadIdx.x;      // 0..511
  const int w  = i >> 6;
  const int l  = i & 63;
  const int l31 = l & 31;
  const int kh  = l >> 5;          // k-half 0..1 (8 k each)
  const int wr = w >> 2;           // wave row 0..1 (128 out rows)
  const int wc = w & 3;            // wave col 0..3 (64 out cols)

  const int nT = K >> 6;           // BK = 64

  // ---- staging (unchanged from r7): thread i -> granules i, i+512 per half.
  const int r0 = i >> 3;
  const int clog = (i & 7) ^ (r0 & 7);
  const uint16_t* aSrc = A + (size_t)(row0 + r0) * K + clog * 8;
  const uint16_t* bSrc = B + (size_t)(col0 + r0) * K + clog * 8;
  uint16_t* ldsu = lds;

#define GL(srcp, dstp)                                                     \
  __builtin_amdgcn_global_load_lds(                                        \
      (const __attribute__((address_space(1))) void*)(srcp),               \
      (__attribute__((address_space(3))) void*)(dstp), 16, 0, 0)

#define STAGE_A(TT, HH)                                                    \
  do {                                                                     \
    const uint16_t* _s = aSrc + (size_t)(HH) * 128 * K + (size_t)(TT) * 64;\
    uint16_t* _d = ldsu + (((TT) & 1) * 32768) + (HH) * 8192 + i * 8;      \
    GL(_s, _d); GL(_s + (size_t)64 * K, _d + 4096);                        \
  } while (0)

#define STAGE_B(TT, HH)                                                    \
  do {                                                                     \
    const uint16_t* _s = bSrc + (size_t)(HH) * 128 * K + (size_t)(TT) * 64;\
    uint16_t* _d = ldsu + (((TT) & 1) * 32768) + 16384 + (HH) * 8192 + i * 8; \
    GL(_s, _d); GL(_s + (size_t)64 * K, _d + 4096);                        \
  } while (0)

  // ---- ds_read byte offsets for 32x32 frags.  [mg][s2] / [ng][s2]
  // A row in wave panel: mg*32 + l31 -> 64-subtile mh=(mg>>1), rr=(mg&1)*32+l31.
  // granule slot = (s2*2 + kh) ^ (l&7)  (rr&7 == l&7 since offsets = 0 mod 8).
  int offA[4][4], offB[2][4];
#pragma unroll
  for (int mg = 0; mg < 4; ++mg) {
    const int rr = (mg & 1) * 32 + l31;
#pragma unroll
    for (int s2 = 0; s2 < 4; ++s2)
      offA[mg][s2] = wr * 16384 + (mg >> 1) * 8192 + rr * 128 +
                     (((s2 * 2 + kh) ^ (l & 7)) * 16);
  }
#pragma unroll
  for (int ng = 0; ng < 2; ++ng) {
    const int rr = (wc & 1) * 64 + ng * 32 + l31;
#pragma unroll
    for (int s2 = 0; s2 < 4; ++s2)
      offB[ng][s2] = 32768 + (wc >> 1) * 16384 + rr * 128 +
                     (((s2 * 2 + kh) ^ (l & 7)) * 16);
  }

  f32x16 acc[4][2] = {};
  bf16x8 aF[4], bF[2];

  // ---- prologue: tile0 all halves + tile1 B halves; drain tile0
  STAGE_A(0, 0); STAGE_A(0, 1); STAGE_B(0, 0); STAGE_B(0, 1);
  if (nT > 1) {
    STAGE_B(1, 0); STAGE_B(1, 1);
    asm volatile("s_waitcnt vmcnt(4)" ::: "memory");
  } else {
    asm volatile("s_waitcnt vmcnt(0)" ::: "memory");
  }
  __builtin_amdgcn_s_barrier();
  __builtin_amdgcn_sched_barrier(0);

  for (int T = 0; T < nT; ++T) {
    const char* bb = (const char*)lds + (T & 1) * 65536;
    const bool stg1 = (T + 1) < nT;
    const bool stg2 = (T + 2) < nT;

#pragma unroll
    for (int s2 = 0; s2 < 4; ++s2) {
      // reads for this k-step
#pragma unroll
      for (int mg = 0; mg < 4; ++mg)
        aF[mg] = *reinterpret_cast<const bf16x8*>(bb + offA[mg][s2]);
#pragma unroll
      for (int ng = 0; ng < 2; ++ng)
        bF[ng] = *reinterpret_cast<const bf16x8*>(bb + offB[ng][s2]);
      // staging interleave (r7 placement)
      if (s2 == 0 && stg1) STAGE_A(T + 1, 0);
      if (s2 == 1 && stg1) STAGE_A(T + 1, 1);
      if (s2 == 3 && stg2) { STAGE_B(T + 2, 0); STAGE_B(T + 2, 1); }
      __builtin_amdgcn_s_setprio(1);
#pragma unroll
      for (int mg = 0; mg < 4; ++mg)
#pragma unroll
        for (int ng = 0; ng < 2; ++ng)
          acc[mg][ng] = __builtin_amdgcn_mfma_f32_32x32x16_bf16(
              aF[mg], bF[ng], acc[mg][ng], 0, 0, 0);
      __builtin_amdgcn_s_setprio(0);
    }

    // ---------- boundary: counted vmcnt (never 0 in steady state), barrier
    if (stg2) {
      asm volatile("s_waitcnt vmcnt(4)" ::: "memory");
    } else {
      asm volatile("s_waitcnt vmcnt(0)" ::: "memory");
    }
    __builtin_amdgcn_s_barrier();
    __builtin_amdgcn_sched_barrier(0);
  }

  // ---- epilogue: C/D 32x32 layout col=lane&31, row=(r&3)+8*(r>>2)+4*kh
#pragma unroll
  for (int mg = 0; mg < 4; ++mg)
#pragma unroll
    for (int ng = 0; ng < 2; ++ng)
#pragma unroll
      for (int r = 0; r < 16; ++r) {
        const int row = row0 + wr * 128 + mg * 32 + (r & 3) + 8 * (r >> 2) + 4 * kh;
        const int col = col0 + wc * 64 + ng * 32 + l31;
        __hip_bfloat16 bv = __float2bfloat16(acc[mg][ng][r]);
        C[(size_t)row * V + col] = *reinterpret_cast<const uint16_t*>(&bv);
      }
#undef STAGE_A
#undef STAGE_B
#undef GL
}

// ---------------------------------------------------------------- JSD rows
__device__ __forceinline__ void unpack8(uint4 v, float* f) {
  uint32_t w[4] = {v.x, v.y, v.z, v.w};
#pragma unroll
  for (int j = 0; j < 4; ++j) {
    union { uint32_t u; float x; } lo, hi;
    lo.u = (w[j] & 0xffffu) << 16;
    hi.u = w[j] & 0xffff0000u;
    f[2 * j] = lo.x;
    f[2 * j + 1] = hi.x;
  }
}

__device__ __forceinline__ float blockReduce(float v, float* sh) {
#pragma unroll
  for (int o = 32; o >= 1; o >>= 1) v += __shfl_xor(v, o, 64);
  const int w = threadIdx.x >> 6;
  __syncthreads();
  if ((threadIdx.x & 63) == 0) sh[w] = v;
  __syncthreads();
  float r = sh[0];
#pragma unroll
  for (int i = 1; i < 4; ++i) r += sh[i];
  return r;
}

// online-LSE load pass (1 global sweep, fused max+sum) + 1 LDS JSD pass.
__global__ __launch_bounds__(256) void jsd_rows_kernel(
    const uint16_t* __restrict__ SL, const uint16_t* __restrict__ TL,
    float* __restrict__ per_tok, int V) {
  __shared__ __align__(16) uint16_t rowS[32000];
  __shared__ __align__(16) uint16_t rowT[32000];
  __shared__ float redM[2][4], redS[2][4], red[4];

  const int t = threadIdx.x;
  const int row = blockIdx.x;
  const uint4* gS = reinterpret_cast<const uint4*>(SL + (size_t)row * V);
  const uint4* gT = reinterpret_cast<const uint4*>(TL + (size_t)row * V);
  uint4* lS = reinterpret_cast<uint4*>(rowS);
  uint4* lT = reinterpret_cast<uint4*>(rowT);
  const int nvec = V >> 3;  // 4000

  float mS = -3.0e38f, sS = 0.f, mT = -3.0e38f, sT = 0.f;
  for (int i = t; i < nvec; i += 256) {
    uint4 vs = gS[i], vt = gT[i];
    lS[i] = vs; lT[i] = vt;
    float fs[8], ft[8];
    unpack8(vs, fs);
    unpack8(vt, ft);
    float vmS = fs[0], vmT = ft[0];
#pragma unroll
    for (int j = 1; j < 8; ++j) { vmS = fmaxf(vmS, fs[j]); vmT = fmaxf(vmT, ft[j]); }
    if (vmS > mS) { sS *= __expf(mS - vmS); mS = vmS; }
    if (vmT > mT) { sT *= __expf(mT - vmT); mT = vmT; }
#pragma unroll
    for (int j = 0; j < 8; ++j) { sS += __expf(fs[j] - mS); sT += __expf(ft[j] - mT); }
  }

  // wave-level (m,s) butterfly merge
#pragma unroll
  for (int o = 32; o >= 1; o >>= 1) {
    float mo = __shfl_xor(mS, o, 64), so = __shfl_xor(sS, o, 64);
    float mn = fmaxf(mS, mo);
    sS = sS * __expf(mS - mn) + so * __expf(mo - mn); mS = mn;
    mo = __shfl_xor(mT, o, 64); so = __shfl_xor(sT, o, 64);
    mn = fmaxf(mT, mo);
    sT = sT * __expf(mT - mn) + so * __expf(mo - mn); mT = mn;
  }
  const int wv = t >> 6;
  if ((t & 63) == 0) {
    redM[0][wv] = mS; redS[0][wv] = sS;
    redM[1][wv] = mT; redS[1][wv] = sT;
  }
  __syncthreads();   // covers (m,s) publication AND the LDS row writes
  float M0 = redM[0][0], S0 = redS[0][0];
  float M1 = redM[1][0], S1 = redS[1][0];
#pragma unroll
  for (int k = 1; k < 4; ++k) {
    float m2 = redM[0][k], s2 = redS[0][k];
    float mn = fmaxf(M0, m2);
    S0 = S0 * __expf(M0 - mn) + s2 * __expf(m2 - mn); M0 = mn;
    m2 = redM[1][k]; s2 = redS[1][k];
    mn = fmaxf(M1, m2);
    S1 = S1 * __expf(M1 - mn) + s2 * __expf(m2 - mn); M1 = mn;
  }
  const float lseS = M0 + __logf(S0);
  const float lseT = M1 + __logf(S1);

  // JSD pass from LDS (student->Q, teacher->P)
  float acc = 0.f;
  for (int i = t; i < nvec; i += 256) {
    float fs[8], ft[8];
    unpack8(lS[i], fs);
    unpack8(lT[i], ft);
#pragma unroll
    for (int j = 0; j < 8; ++j) {
      const float lq = fs[j] - lseS;
      const float lp = ft[j] - lseT;
      const float q = __expf(lq);
      const float p = __expf(lp);
      const float m = BETA * p + (1.f - BETA) * q;
      const float lm = __logf(m);
      acc += BETA * p * (lp - lm) + (1.f - BETA) * q * (lq - lm);
    }
  }
  acc = blockReduce(acc, red);
  if (t == 0) per_tok[row] = acc;
}

// ---------------------------------------------------------------- finalize
__global__ __launch_bounds__(256) void finalize_kernel(
    const float* __restrict__ per_tok, const int* __restrict__ tgt,
    float* __restrict__ out, int N) {
  __shared__ float redf[4];
  __shared__ int redi[4];
  float s = 0.f;
  int c = 0;
  for (int i = threadIdx.x; i < N; i += 256) {
    if (tgt[i] != IGNORE_INDEX) { s += per_tok[i]; c += 1; }
  }
#pragma unroll
  for (int o = 32; o >= 1; o >>= 1) {
    s += __shfl_xor(s, o, 64);
    c += __shfl_xor(c, o, 64);
  }
  const int w = threadIdx.x >> 6;
  if ((threadIdx.x & 63) == 0) { redf[w] = s; redi[w] = c; }
  __syncthreads();
  if (threadIdx.x == 0) {
    float st = 0.f;
    int ct = 0;
#pragma unroll
    for (int i = 0; i < 4; ++i) { st += redf[i]; ct += redi[i]; }
    out[0] = st / (float)(ct > 0 ? ct : 1);
  }
}

// ---------------------------------------------------------------- launch
extern "C" void kernel_launch(void* const* d_in, const int* in_sizes, int n_in,
                              void* d_out, int out_size, void* d_ws, size_t ws_size,
                              hipStream_t stream) {
  const float* student = (const float*)d_in[0];
  const float* W_s     = (const float*)d_in[1];
  const float* teacher = (const float*)d_in[2];
  const float* W_t     = (const float*)d_in[3];
  const int*   target  = (const int*)d_in[4];

  const int N  = in_sizes[4];            // 2048
  const int Hs = in_sizes[0] / N;        // 2048
  const int Ht = in_sizes[2] / N;        // 4096
  const int V  = in_sizes[1] / Hs;       // 32000

  char* ws = (char*)d_ws;
  size_t off = 0;
  auto alloc = [&](size_t bytes) -> void* {
    void* p = ws + off;
    off += (bytes + 255) & ~(size_t)255;
    return p;
  };
  uint16_t* Sbf  = (uint16_t*)alloc((size_t)N * Hs * 2);
  uint16_t* Wsbf = (uint16_t*)alloc((size_t)V * Hs * 2);
  uint16_t* Tbf  = (uint16_t*)alloc((size_t)N * Ht * 2);
  uint16_t* Wtbf = (uint16_t*)alloc((size_t)V * Ht * 2);
  uint16_t* slog = (uint16_t*)alloc((size_t)N * V * 2);
  uint16_t* tlog = (uint16_t*)alloc((size_t)N * V * 2);
  float* per_tok = (float*)alloc((size_t)N * sizeof(float));
  (void)ws_size;  // total ~681 MB

  f32_to_bf16_kernel<<<1024, 256, 0, stream>>>(student, Sbf, N * Hs);
  f32_to_bf16_kernel<<<2048, 256, 0, stream>>>(W_s, Wsbf, V * Hs);
  f32_to_bf16_kernel<<<1024, 256, 0, stream>>>(teacher, Tbf, N * Ht);
  f32_to_bf16_kernel<<<2048, 256, 0, stream>>>(W_t, Wtbf, V * Ht);

  const int RT = N / 256;   // 8
  const int CT = V / 256;   // 125
  // merged launch: teacher blocks first, student backfills the tail
  gemm32_kernel<<<2 * RT * CT, 512, 0, stream>>>(
      Tbf, Wtbf, tlog, Ht, Sbf, Wsbf, slog, Hs, V, RT, CT);

  jsd_rows_kernel<<<N, 256, 0, stream>>>(slog, tlog, per_tok, V);
  finalize_kernel<<<1, 256, 0, stream>>>(per_tok, target, (float*)d_out, N);
}

// Round 10
// 1028.478 us; speedup vs baseline: 1.2881x; 1.0965x over previous
//
#include <hip/hip_runtime.h>
#include <hip/hip_bf16.h>
#include <stdint.h>

#define BETA 0.5f
#define IGNORE_INDEX (-100)

typedef short bf16x8 __attribute__((ext_vector_type(8)));
typedef float f32x4 __attribute__((ext_vector_type(4)));

// ---------------------------------------------------------------- converts
// 8 floats per thread per iter (two float4), grid-stride.
__global__ __launch_bounds__(256) void f32_to_bf16_kernel(
    const float* __restrict__ in, uint16_t* __restrict__ out, int n) {
  int i = (blockIdx.x * blockDim.x + threadIdx.x) * 8;
  const int stride = gridDim.x * blockDim.x * 8;
  for (; i < n; i += stride) {
    float4 v0 = *reinterpret_cast<const float4*>(in + i);
    float4 v1 = *reinterpret_cast<const float4*>(in + i + 4);
    auto cv = [](float x) -> uint16_t {
      __hip_bfloat16 h = __float2bfloat16(x);
      return *reinterpret_cast<const uint16_t*>(&h);
    };
    ushort4 o0, o1;
    o0.x = cv(v0.x); o0.y = cv(v0.y); o0.z = cv(v0.z); o0.w = cv(v0.w);
    o1.x = cv(v1.x); o1.y = cv(v1.y); o1.z = cv(v1.z); o1.w = cv(v1.w);
    *reinterpret_cast<ushort4*>(out + i) = o0;
    *reinterpret_cast<ushort4*>(out + i + 4) = o1;
  }
}

// ---------------------------------------------------------------- GEMM (NT)
// r7 kernel VERBATIM (best measured: 685 us, MfmaUtil 55%, 0 conflicts).
// C[n][v] = sum_k A[n][k]*B[v][k].  256x256 tile, BK=64, 8 waves (2Mx4N).
// Barrier-free tile body + conflict-free granule XOR layout; one boundary
// barrier per K-tile with counted vmcnt(4).  16x16x32 MFMA.
__global__ __launch_bounds__(512, 2) void gemm_ov_kernel(
    const uint16_t* __restrict__ At, const uint16_t* __restrict__ Bt,
    uint16_t* __restrict__ Ct, int Kt,
    const uint16_t* __restrict__ As_, const uint16_t* __restrict__ Bs_,
    uint16_t* __restrict__ Cs, int Ks,
    int V, int RT, int CT) {
  __shared__ __align__(16) uint16_t lds[65536];

  const int half = RT * CT;
  const uint16_t *A, *B;
  uint16_t* C;
  int K, bidx = blockIdx.x;
  if (bidx < half) { A = At; B = Bt; C = Ct; K = Kt; }
  else             { A = As_; B = Bs_; C = Cs; K = Ks; bidx -= half; }

  int L = ((half & 7) == 0) ? ((bidx & 7) * (half >> 3) + (bidx >> 3)) : bidx;
  const int rt = L % RT;
  const int ct = L / RT;
  const int row0 = rt * 256;
  const int col0 = ct * 256;

  const int i  = threadIdx.x;      // 0..511
  const int w  = i >> 6;
  const int l  = i & 63;
  const int wl = l & 15;
  const int kg = l >> 4;
  const int wr = w >> 2;           // wave row 0..1 (128 out rows)
  const int wc = w & 3;            // wave col 0..3 (64 out cols)

  const int nT = K >> 6;           // BK = 64

  const int r0 = i >> 3;
  const int clog = (i & 7) ^ (r0 & 7);
  const uint16_t* aSrc = A + (size_t)(row0 + r0) * K + clog * 8;
  const uint16_t* bSrc = B + (size_t)(col0 + r0) * K + clog * 8;
  uint16_t* ldsu = lds;

#define GL(srcp, dstp)                                                     \
  __builtin_amdgcn_global_load_lds(                                        \
      (const __attribute__((address_space(1))) void*)(srcp),               \
      (__attribute__((address_space(3))) void*)(dstp), 16, 0, 0)

#define STAGE_A(TT, HH)                                                    \
  do {                                                                     \
    const uint16_t* _s = aSrc + (size_t)(HH) * 128 * K + (size_t)(TT) * 64;\
    uint16_t* _d = ldsu + (((TT) & 1) * 32768) + (HH) * 8192 + i * 8;      \
    GL(_s, _d); GL(_s + (size_t)64 * K, _d + 4096);                        \
  } while (0)

#define STAGE_B(TT, HH)                                                    \
  do {                                                                     \
    const uint16_t* _s = bSrc + (size_t)(HH) * 128 * K + (size_t)(TT) * 64;\
    uint16_t* _d = ldsu + (((TT) & 1) * 32768) + 16384 + (HH) * 8192 + i * 8; \
    GL(_s, _d); GL(_s + (size_t)64 * K, _d + 4096);                        \
  } while (0)

  int offA[8][2], offB[4][2];
#pragma unroll
  for (int m = 0; m < 8; ++m) {
    const int rho = (m & 3) * 16 + wl;
    const int mh = m >> 2;
#pragma unroll
    for (int s = 0; s < 2; ++s)
      offA[m][s] = wr * 16384 + mh * 8192 + rho * 128 +
                   (((s * 4 + kg) ^ (wl & 7)) * 16);
  }
#pragma unroll
  for (int n = 0; n < 4; ++n) {
    const int sig = (wc & 1) * 64 + n * 16 + wl;
#pragma unroll
    for (int s = 0; s < 2; ++s)
      offB[n][s] = 32768 + (wc >> 1) * 16384 + sig * 128 +
                   (((s * 4 + kg) ^ (wl & 7)) * 16);
  }

  f32x4 acc[8][4] = {};
  bf16x8 af[4], bf[4], ag[4];

  STAGE_A(0, 0); STAGE_A(0, 1); STAGE_B(0, 0); STAGE_B(0, 1);
  if (nT > 1) {
    STAGE_B(1, 0); STAGE_B(1, 1);
    asm volatile("s_waitcnt vmcnt(4)" ::: "memory");
  } else {
    asm volatile("s_waitcnt vmcnt(0)" ::: "memory");
  }
  __builtin_amdgcn_s_barrier();
  __builtin_amdgcn_sched_barrier(0);

  for (int T = 0; T < nT; ++T) {
    const char* bb = (const char*)lds + (T & 1) * 65536;
    const bool stg1 = (T + 1) < nT;
    const bool stg2 = (T + 2) < nT;

    // chunk 1: read A(mh0,s0)+B(s0); stage A0(T+1); MFMA m0..3 s0
#pragma unroll
    for (int m = 0; m < 4; ++m)
      af[m] = *reinterpret_cast<const bf16x8*>(bb + offA[m][0]);
#pragma unroll
    for (int n = 0; n < 4; ++n)
      bf[n] = *reinterpret_cast<const bf16x8*>(bb + offB[n][0]);
    if (stg1) STAGE_A(T + 1, 0);
    __builtin_amdgcn_s_setprio(1);
#pragma unroll
    for (int m = 0; m < 4; ++m)
#pragma unroll
      for (int n = 0; n < 4; ++n)
        acc[m][n] = __builtin_amdgcn_mfma_f32_16x16x32_bf16(
            af[m], bf[n], acc[m][n], 0, 0, 0);
    __builtin_amdgcn_s_setprio(0);

    // chunk 2: read A(mh1,s0); stage A1(T+1); MFMA m4..7 s0
#pragma unroll
    for (int m = 0; m < 4; ++m)
      ag[m] = *reinterpret_cast<const bf16x8*>(bb + offA[4 + m][0]);
    if (stg1) STAGE_A(T + 1, 1);
    __builtin_amdgcn_s_setprio(1);
#pragma unroll
    for (int m = 0; m < 4; ++m)
#pragma unroll
      for (int n = 0; n < 4; ++n)
        acc[4 + m][n] = __builtin_amdgcn_mfma_f32_16x16x32_bf16(
            ag[m], bf[n], acc[4 + m][n], 0, 0, 0);
    __builtin_amdgcn_s_setprio(0);

    // chunk 3: read A(mh0,s1)+B(s1); MFMA m0..3 s1
#pragma unroll
    for (int m = 0; m < 4; ++m)
      af[m] = *reinterpret_cast<const bf16x8*>(bb + offA[m][1]);
#pragma unroll
    for (int n = 0; n < 4; ++n)
      bf[n] = *reinterpret_cast<const bf16x8*>(bb + offB[n][1]);
    __builtin_amdgcn_s_setprio(1);
#pragma unroll
    for (int m = 0; m < 4; ++m)
#pragma unroll
      for (int n = 0; n < 4; ++n)
        acc[m][n] = __builtin_amdgcn_mfma_f32_16x16x32_bf16(
            af[m], bf[n], acc[m][n], 0, 0, 0);
    __builtin_amdgcn_s_setprio(0);

    // chunk 4: read A(mh1,s1); stage B0+B1(T+2); MFMA m4..7 s1
#pragma unroll
    for (int m = 0; m < 4; ++m)
      ag[m] = *reinterpret_cast<const bf16x8*>(bb + offA[4 + m][1]);
    if (stg2) { STAGE_B(T + 2, 0); STAGE_B(T + 2, 1); }
    __builtin_amdgcn_s_setprio(1);
#pragma unroll
    for (int m = 0; m < 4; ++m)
#pragma unroll
      for (int n = 0; n < 4; ++n)
        acc[4 + m][n] = __builtin_amdgcn_mfma_f32_16x16x32_bf16(
            ag[m], bf[n], acc[4 + m][n], 0, 0, 0);
    __builtin_amdgcn_s_setprio(0);

    // boundary: counted vmcnt (never 0 in steady state), barrier
    if (stg2) {
      asm volatile("s_waitcnt vmcnt(4)" ::: "memory");
    } else {
      asm volatile("s_waitcnt vmcnt(0)" ::: "memory");
    }
    __builtin_amdgcn_s_barrier();
    __builtin_amdgcn_sched_barrier(0);
  }

  // epilogue: C/D layout col=lane&15, row=(lane>>4)*4+reg
#pragma unroll
  for (int mg = 0; mg < 8; ++mg)
#pragma unroll
    for (int ng = 0; ng < 4; ++ng)
#pragma unroll
      for (int r = 0; r < 4; ++r) {
        const int row = row0 + wr * 128 + mg * 16 + kg * 4 + r;
        const int col = col0 + wc * 64 + ng * 16 + wl;
        __hip_bfloat16 bv = __float2bfloat16(acc[mg][ng][r]);
        C[(size_t)row * V + col] = *reinterpret_cast<const uint16_t*>(&bv);
      }
#undef STAGE_A
#undef STAGE_B
#undef GL
}

// ---------------------------------------------------------------- JSD rows
__device__ __forceinline__ void unpack8(uint4 v, float* f) {
  uint32_t w[4] = {v.x, v.y, v.z, v.w};
#pragma unroll
  for (int j = 0; j < 4; ++j) {
    union { uint32_t u; float x; } lo, hi;
    lo.u = (w[j] & 0xffffu) << 16;
    hi.u = w[j] & 0xffff0000u;
    f[2 * j] = lo.x;
    f[2 * j + 1] = hi.x;
  }
}

__device__ __forceinline__ float blockReduce(float v, float* sh) {
#pragma unroll
  for (int o = 32; o >= 1; o >>= 1) v += __shfl_xor(v, o, 64);
  const int w = threadIdx.x >> 6;
  __syncthreads();
  if ((threadIdx.x & 63) == 0) sh[w] = v;
  __syncthreads();
  float r = sh[0];
#pragma unroll
  for (int i = 1; i < 4; ++i) r += sh[i];
  return r;
}

// online-LSE load pass (1 global sweep, fused max+sum) + 1 LDS JSD pass.
__global__ __launch_bounds__(256) void jsd_rows_kernel(
    const uint16_t* __restrict__ SL, const uint16_t* __restrict__ TL,
    float* __restrict__ per_tok, int V) {
  __shared__ __align__(16) uint16_t rowS[32000];
  __shared__ __align__(16) uint16_t rowT[32000];
  __shared__ float redM[2][4], redS[2][4], red[4];

  const int t = threadIdx.x;
  const int row = blockIdx.x;
  const uint4* gS = reinterpret_cast<const uint4*>(SL + (size_t)row * V);
  const uint4* gT = reinterpret_cast<const uint4*>(TL + (size_t)row * V);
  uint4* lS = reinterpret_cast<uint4*>(rowS);
  uint4* lT = reinterpret_cast<uint4*>(rowT);
  const int nvec = V >> 3;  // 4000

  float mS = -3.0e38f, sS = 0.f, mT = -3.0e38f, sT = 0.f;
  for (int i = t; i < nvec; i += 256) {
    uint4 vs = gS[i], vt = gT[i];
    lS[i] = vs; lT[i] = vt;
    float fs[8], ft[8];
    unpack8(vs, fs);
    unpack8(vt, ft);
    float vmS = fs[0], vmT = ft[0];
#pragma unroll
    for (int j = 1; j < 8; ++j) { vmS = fmaxf(vmS, fs[j]); vmT = fmaxf(vmT, ft[j]); }
    if (vmS > mS) { sS *= __expf(mS - vmS); mS = vmS; }
    if (vmT > mT) { sT *= __expf(mT - vmT); mT = vmT; }
#pragma unroll
    for (int j = 0; j < 8; ++j) { sS += __expf(fs[j] - mS); sT += __expf(ft[j] - mT); }
  }

#pragma unroll
  for (int o = 32; o >= 1; o >>= 1) {
    float mo = __shfl_xor(mS, o, 64), so = __shfl_xor(sS, o, 64);
    float mn = fmaxf(mS, mo);
    sS = sS * __expf(mS - mn) + so * __expf(mo - mn); mS = mn;
    mo = __shfl_xor(mT, o, 64); so = __shfl_xor(sT, o, 64);
    mn = fmaxf(mT, mo);
    sT = sT * __expf(mT - mn) + so * __expf(mo - mn); mT = mn;
  }
  const int wv = t >> 6;
  if ((t & 63) == 0) {
    redM[0][wv] = mS; redS[0][wv] = sS;
    redM[1][wv] = mT; redS[1][wv] = sT;
  }
  __syncthreads();   // covers (m,s) publication AND the LDS row writes
  float M0 = redM[0][0], S0 = redS[0][0];
  float M1 = redM[1][0], S1 = redS[1][0];
#pragma unroll
  for (int k = 1; k < 4; ++k) {
    float m2 = redM[0][k], s2 = redS[0][k];
    float mn = fmaxf(M0, m2);
    S0 = S0 * __expf(M0 - mn) + s2 * __expf(m2 - mn); M0 = mn;
    m2 = redM[1][k]; s2 = redS[1][k];
    mn = fmaxf(M1, m2);
    S1 = S1 * __expf(M1 - mn) + s2 * __expf(m2 - mn); M1 = mn;
  }
  const float lseS = M0 + __logf(S0);
  const float lseT = M1 + __logf(S1);

  float acc = 0.f;
  for (int i = t; i < nvec; i += 256) {
    float fs[8], ft[8];
    unpack8(lS[i], fs);
    unpack8(lT[i], ft);
#pragma unroll
    for (int j = 0; j < 8; ++j) {
      const float lq = fs[j] - lseS;
      const float lp = ft[j] - lseT;
      const float q = __expf(lq);
      const float p = __expf(lp);
      const float m = BETA * p + (1.f - BETA) * q;
      const float lm = __logf(m);
      acc += BETA * p * (lp - lm) + (1.f - BETA) * q * (lq - lm);
    }
  }
  acc = blockReduce(acc, red);
  if (t == 0) per_tok[row] = acc;
}

// ---------------------------------------------------------------- finalize
__global__ __launch_bounds__(256) void finalize_kernel(
    const float* __restrict__ per_tok, const int* __restrict__ tgt,
    float* __restrict__ out, int N) {
  __shared__ float redf[4];
  __shared__ int redi[4];
  float s = 0.f;
  int c = 0;
  for (int i = threadIdx.x; i < N; i += 256) {
    if (tgt[i] != IGNORE_INDEX) { s += per_tok[i]; c += 1; }
  }
#pragma unroll
  for (int o = 32; o >= 1; o >>= 1) {
    s += __shfl_xor(s, o, 64);
    c += __shfl_xor(c, o, 64);
  }
  const int w = threadIdx.x >> 6;
  if ((threadIdx.x & 63) == 0) { redf[w] = s; redi[w] = c; }
  __syncthreads();
  if (threadIdx.x == 0) {
    float st = 0.f;
    int ct = 0;
#pragma unroll
    for (int i = 0; i < 4; ++i) { st += redf[i]; ct += redi[i]; }
    out[0] = st / (float)(ct > 0 ? ct : 1);
  }
}

// ---------------------------------------------------------------- launch
extern "C" void kernel_launch(void* const* d_in, const int* in_sizes, int n_in,
                              void* d_out, int out_size, void* d_ws, size_t ws_size,
                              hipStream_t stream) {
  const float* student = (const float*)d_in[0];
  const float* W_s     = (const float*)d_in[1];
  const float* teacher = (const float*)d_in[2];
  const float* W_t     = (const float*)d_in[3];
  const int*   target  = (const int*)d_in[4];

  const int N  = in_sizes[4];            // 2048
  const int Hs = in_sizes[0] / N;        // 2048
  const int Ht = in_sizes[2] / N;        // 4096
  const int V  = in_sizes[1] / Hs;       // 32000

  char* ws = (char*)d_ws;
  size_t off = 0;
  auto alloc = [&](size_t bytes) -> void* {
    void* p = ws + off;
    off += (bytes + 255) & ~(size_t)255;
    return p;
  };
  uint16_t* Sbf  = (uint16_t*)alloc((size_t)N * Hs * 2);
  uint16_t* Wsbf = (uint16_t*)alloc((size_t)V * Hs * 2);
  uint16_t* Tbf  = (uint16_t*)alloc((size_t)N * Ht * 2);
  uint16_t* Wtbf = (uint16_t*)alloc((size_t)V * Ht * 2);
  uint16_t* slog = (uint16_t*)alloc((size_t)N * V * 2);
  uint16_t* tlog = (uint16_t*)alloc((size_t)N * V * 2);
  float* per_tok = (float*)alloc((size_t)N * sizeof(float));
  (void)ws_size;  // total ~681 MB

  f32_to_bf16_kernel<<<512, 256, 0, stream>>>(student, Sbf, N * Hs);
  f32_to_bf16_kernel<<<4096, 256, 0, stream>>>(W_s, Wsbf, V * Hs);
  f32_to_bf16_kernel<<<512, 256, 0, stream>>>(teacher, Tbf, N * Ht);
  f32_to_bf16_kernel<<<4096, 256, 0, stream>>>(W_t, Wtbf, V * Ht);

  const int RT = N / 256;   // 8
  const int CT = V / 256;   // 125
  // merged launch: teacher blocks first, student backfills the tail
  gemm_ov_kernel<<<2 * RT * CT, 512, 0, stream>>>(
      Tbf, Wtbf, tlog, Ht, Sbf, Wsbf, slog, Hs, V, RT, CT);

  jsd_rows_kernel<<<N, 256, 0, stream>>>(slog, tlog, per_tok, V);
  finalize_kernel<<<1, 256, 0, stream>>>(per_tok, target, (float*)d_out, N);
}

// Round 11
// 922.651 us; speedup vs baseline: 1.4358x; 1.1147x over previous
//
#include <hip/hip_runtime.h>
#include <hip/hip_bf16.h>
#include <hip/hip_fp8.h>
#include <stdint.h>

#define BETA 0.5f
#define IGNORE_INDEX (-100)
// Weights are pre-scaled x64 into fp8 (moves sigma~1/64 weights out of the
// e4m3 subnormal range); the GEMM epilogue multiplies by 1/64.
#define WSCALE 64.0f
#define INV_WSCALE 0.015625f

typedef float f32x4 __attribute__((ext_vector_type(4)));

// ---------------------------------------------------------------- converts
// f32 -> fp8 e4m3 (OCP), 8 elements/thread, optional pre-scale.
__global__ __launch_bounds__(256) void f32_to_fp8_kernel(
    const float* __restrict__ in, uint8_t* __restrict__ out, int n, float scale) {
  int i = (blockIdx.x * blockDim.x + threadIdx.x) * 8;
  const int stride = gridDim.x * blockDim.x * 8;
  for (; i < n; i += stride) {
    float4 v0 = *reinterpret_cast<const float4*>(in + i);
    float4 v1 = *reinterpret_cast<const float4*>(in + i + 4);
    const float f[8] = {v0.x, v0.y, v0.z, v0.w, v1.x, v1.y, v1.z, v1.w};
    union { uint8_t b[8]; uint2 u; } o;
#pragma unroll
    for (int j = 0; j < 8; ++j) {
      __hip_fp8_e4m3 h(f[j] * scale);
      o.b[j] = h.__x;
    }
    *reinterpret_cast<uint2*>(out + i) = o.u;
  }
}

// ---------------------------------------------------------------- GEMM (NT)
// C[n][v] = (1/64) * sum_k A[n][k]*B[v][k], A/B fp8 e4m3 (B pre-scaled x64),
// C bf16.  256x256 tile, BK=64, 8 waves (2Mx4N), r7/r10 schedule: barrier-
// free tile body, one boundary barrier per K-tile, counted vmcnt (T3+T4),
// setprio (T5), XCD swizzle (T1).  fp8 halves LDS traffic: A/B tiles are
// 16 KB each, reads are ds_read_b64 (~6 cyc), LDS total 64 KiB.
// Row layout: 64 B/row = 8 octets of 8 B; phys octet = logical ^ (row&6)
// (bit0 preserved so the 16 B gload_lds granule keeps source half-order;
// b64 reads then alias max 2-way = free).  Staging: thread i stages
// granules i (rows 0..127) and i+512 (rows 128..255); granule (row rg,
// phys slot q) sources logical slot q ^ ((rg>>1)&3) of the row.
// MFMA: f32_16x16x32_fp8_fp8, frag = 8 fp8/lane (row=l&15, k=kg*8+j);
// C/D layout dtype-independent (m121-128).
// Merged launch: blocks [0,half) = teacher, [half,2*half) = student.

__global__ __launch_bounds__(512, 2) void gemm_f8_kernel(
    const uint8_t* __restrict__ At, const uint8_t* __restrict__ Bt,
    uint16_t* __restrict__ Ct, int Kt,
    const uint8_t* __restrict__ As_, const uint8_t* __restrict__ Bs_,
    uint16_t* __restrict__ Cs, int Ks,
    int V, int RT, int CT) {
  __shared__ __align__(16) uint8_t lds[65536];  // 2 buf x (A 16K | B 16K)

  const int half = RT * CT;
  const uint8_t *A, *B;
  uint16_t* C;
  int K, bidx = blockIdx.x;
  if (bidx < half) { A = At; B = Bt; C = Ct; K = Kt; }
  else             { A = As_; B = Bs_; C = Cs; K = Ks; bidx -= half; }

  int L = ((half & 7) == 0) ? ((bidx & 7) * (half >> 3) + (bidx >> 3)) : bidx;
  const int rt = L % RT;
  const int ct = L / RT;
  const int row0 = rt * 256;
  const int col0 = ct * 256;

  const int i  = threadIdx.x;      // 0..511
  const int w  = i >> 6;
  const int l  = i & 63;
  const int wl = l & 15;
  const int kg = l >> 4;
  const int wr = w >> 2;           // wave row 0..1 (128 out rows)
  const int wc = w & 3;            // wave col 0..3 (64 out cols)

  const int nT = K >> 6;           // BK = 64

  // ---- staging: thread i -> granules i (row rg) and i+512 (row rg+128).
  const int rg = i >> 2;           // 0..127
  const int q  = i & 3;
  const int qlog = q ^ ((rg >> 1) & 3);
  const uint8_t* aSrc = A + (size_t)(row0 + rg) * K + qlog * 16;
  const uint8_t* bSrc = B + (size_t)(col0 + rg) * K + qlog * 16;
  uint8_t* ldsu = lds;

#define GL(srcp, dstp)                                                     \
  __builtin_amdgcn_global_load_lds(                                        \
      (const __attribute__((address_space(1))) void*)(srcp),               \
      (__attribute__((address_space(3))) void*)(dstp), 16, 0, 0)

#define STAGE_A(TT)                                                        \
  do {                                                                     \
    const uint8_t* _s = aSrc + (size_t)(TT) * 64;                          \
    uint8_t* _d = ldsu + (((TT) & 1) * 32768) + i * 16;                    \
    GL(_s, _d); GL(_s + (size_t)128 * K, _d + 8192);                       \
  } while (0)

#define STAGE_B(TT)                                                        \
  do {                                                                     \
    const uint8_t* _s = bSrc + (size_t)(TT) * 64;                          \
    uint8_t* _d = ldsu + (((TT) & 1) * 32768) + 16384 + i * 16;            \
    GL(_s, _d); GL(_s + (size_t)128 * K, _d + 8192);                       \
  } while (0)

  // ---- ds_read_b64 byte offsets: row r, octet o = s*4+kg, phys = o^(r&6).
  int offA[8][2], offB[4][2];
#pragma unroll
  for (int m = 0; m < 8; ++m) {
    const int r = wr * 128 + m * 16 + wl;
#pragma unroll
    for (int s = 0; s < 2; ++s)
      offA[m][s] = r * 64 + (((s * 4 + kg) ^ (r & 6)) * 8);
  }
#pragma unroll
  for (int n = 0; n < 4; ++n) {
    const int r = wc * 64 + n * 16 + wl;
#pragma unroll
    for (int s = 0; s < 2; ++s)
      offB[n][s] = 16384 + r * 64 + (((s * 4 + kg) ^ (r & 6)) * 8);
  }

  f32x4 acc[8][4] = {};
  long af[4], bf[4], ag[4];

  // ---- prologue: stage A(0)+B(0) + B(1); wait tile0 (vmcnt 2)
  STAGE_A(0); STAGE_B(0);
  if (nT > 1) {
    STAGE_B(1);
    asm volatile("s_waitcnt vmcnt(2)" ::: "memory");
  } else {
    asm volatile("s_waitcnt vmcnt(0)" ::: "memory");
  }
  __builtin_amdgcn_s_barrier();
  __builtin_amdgcn_sched_barrier(0);

  for (int T = 0; T < nT; ++T) {
    const uint8_t* bb = lds + (T & 1) * 32768;
    const bool stg1 = (T + 1) < nT;
    const bool stg2 = (T + 2) < nT;

    // chunk 1: read A(m0..3,s0)+B(s0); stage A(T+1); MFMA m0..3 s0
#pragma unroll
    for (int m = 0; m < 4; ++m)
      af[m] = *reinterpret_cast<const long*>(bb + offA[m][0]);
#pragma unroll
    for (int n = 0; n < 4; ++n)
      bf[n] = *reinterpret_cast<const long*>(bb + offB[n][0]);
    if (stg1) STAGE_A(T + 1);
    __builtin_amdgcn_s_setprio(1);
#pragma unroll
    for (int m = 0; m < 4; ++m)
#pragma unroll
      for (int n = 0; n < 4; ++n)
        acc[m][n] = __builtin_amdgcn_mfma_f32_16x16x32_fp8_fp8(
            af[m], bf[n], acc[m][n], 0, 0, 0);
    __builtin_amdgcn_s_setprio(0);

    // chunk 2: read A(m4..7,s0); MFMA m4..7 s0
#pragma unroll
    for (int m = 0; m < 4; ++m)
      ag[m] = *reinterpret_cast<const long*>(bb + offA[4 + m][0]);
    __builtin_amdgcn_s_setprio(1);
#pragma unroll
    for (int m = 0; m < 4; ++m)
#pragma unroll
      for (int n = 0; n < 4; ++n)
        acc[4 + m][n] = __builtin_amdgcn_mfma_f32_16x16x32_fp8_fp8(
            ag[m], bf[n], acc[4 + m][n], 0, 0, 0);
    __builtin_amdgcn_s_setprio(0);

    // chunk 3: read A(m0..3,s1)+B(s1); MFMA m0..3 s1
#pragma unroll
    for (int m = 0; m < 4; ++m)
      af[m] = *reinterpret_cast<const long*>(bb + offA[m][1]);
#pragma unroll
    for (int n = 0; n < 4; ++n)
      bf[n] = *reinterpret_cast<const long*>(bb + offB[n][1]);
    __builtin_amdgcn_s_setprio(1);
#pragma unroll
    for (int m = 0; m < 4; ++m)
#pragma unroll
      for (int n = 0; n < 4; ++n)
        acc[m][n] = __builtin_amdgcn_mfma_f32_16x16x32_fp8_fp8(
            af[m], bf[n], acc[m][n], 0, 0, 0);
    __builtin_amdgcn_s_setprio(0);

    // chunk 4: read A(m4..7,s1); stage B(T+2); MFMA m4..7 s1
#pragma unroll
    for (int m = 0; m < 4; ++m)
      ag[m] = *reinterpret_cast<const long*>(bb + offA[4 + m][1]);
    if (stg2) STAGE_B(T + 2);
    __builtin_amdgcn_s_setprio(1);
#pragma unroll
    for (int m = 0; m < 4; ++m)
#pragma unroll
      for (int n = 0; n < 4; ++n)
        acc[4 + m][n] = __builtin_amdgcn_mfma_f32_16x16x32_fp8_fp8(
            ag[m], bf[n], acc[4 + m][n], 0, 0, 0);
    __builtin_amdgcn_s_setprio(0);

    // boundary: counted vmcnt (A(T+1) done, B(T+2) stays in flight), barrier
    if (stg2) {
      asm volatile("s_waitcnt vmcnt(2)" ::: "memory");
    } else {
      asm volatile("s_waitcnt vmcnt(0)" ::: "memory");
    }
    __builtin_amdgcn_s_barrier();
    __builtin_amdgcn_sched_barrier(0);
  }

  // epilogue: C/D layout col=lane&15, row=(lane>>4)*4+reg; x 1/64 (W scale)
#pragma unroll
  for (int mg = 0; mg < 8; ++mg)
#pragma unroll
    for (int ng = 0; ng < 4; ++ng)
#pragma unroll
      for (int r = 0; r < 4; ++r) {
        const int row = row0 + wr * 128 + mg * 16 + kg * 4 + r;
        const int col = col0 + wc * 64 + ng * 16 + wl;
        __hip_bfloat16 bv = __float2bfloat16(acc[mg][ng][r] * INV_WSCALE);
        C[(size_t)row * V + col] = *reinterpret_cast<const uint16_t*>(&bv);
      }
#undef STAGE_A
#undef STAGE_B
#undef GL
}

// ---------------------------------------------------------------- JSD rows
__device__ __forceinline__ void unpack8(uint4 v, float* f) {
  uint32_t w[4] = {v.x, v.y, v.z, v.w};
#pragma unroll
  for (int j = 0; j < 4; ++j) {
    union { uint32_t u; float x; } lo, hi;
    lo.u = (w[j] & 0xffffu) << 16;
    hi.u = w[j] & 0xffff0000u;
    f[2 * j] = lo.x;
    f[2 * j + 1] = hi.x;
  }
}

__device__ __forceinline__ float blockReduce(float v, float* sh) {
#pragma unroll
  for (int o = 32; o >= 1; o >>= 1) v += __shfl_xor(v, o, 64);
  const int w = threadIdx.x >> 6;
  __syncthreads();
  if ((threadIdx.x & 63) == 0) sh[w] = v;
  __syncthreads();
  float r = sh[0];
#pragma unroll
  for (int i = 1; i < 4; ++i) r += sh[i];
  return r;
}

// online-LSE load pass (1 global sweep, fused max+sum) + 1 LDS JSD pass.
__global__ __launch_bounds__(256) void jsd_rows_kernel(
    const uint16_t* __restrict__ SL, const uint16_t* __restrict__ TL,
    float* __restrict__ per_tok, int V) {
  __shared__ __align__(16) uint16_t rowS[32000];
  __shared__ __align__(16) uint16_t rowT[32000];
  __shared__ float redM[2][4], redS[2][4], red[4];

  const int t = threadIdx.x;
  const int row = blockIdx.x;
  const uint4* gS = reinterpret_cast<const uint4*>(SL + (size_t)row * V);
  const uint4* gT = reinterpret_cast<const uint4*>(TL + (size_t)row * V);
  uint4* lS = reinterpret_cast<uint4*>(rowS);
  uint4* lT = reinterpret_cast<uint4*>(rowT);
  const int nvec = V >> 3;  // 4000

  float mS = -3.0e38f, sS = 0.f, mT = -3.0e38f, sT = 0.f;
  for (int i = t; i < nvec; i += 256) {
    uint4 vs = gS[i], vt = gT[i];
    lS[i] = vs; lT[i] = vt;
    float fs[8], ft[8];
    unpack8(vs, fs);
    unpack8(vt, ft);
    float vmS = fs[0], vmT = ft[0];
#pragma unroll
    for (int j = 1; j < 8; ++j) { vmS = fmaxf(vmS, fs[j]); vmT = fmaxf(vmT, ft[j]); }
    if (vmS > mS) { sS *= __expf(mS - vmS); mS = vmS; }
    if (vmT > mT) { sT *= __expf(mT - vmT); mT = vmT; }
#pragma unroll
    for (int j = 0; j < 8; ++j) { sS += __expf(fs[j] - mS); sT += __expf(ft[j] - mT); }
  }

#pragma unroll
  for (int o = 32; o >= 1; o >>= 1) {
    float mo = __shfl_xor(mS, o, 64), so = __shfl_xor(sS, o, 64);
    float mn = fmaxf(mS, mo);
    sS = sS * __expf(mS - mn) + so * __expf(mo - mn); mS = mn;
    mo = __shfl_xor(mT, o, 64); so = __shfl_xor(sT, o, 64);
    mn = fmaxf(mT, mo);
    sT = sT * __expf(mT - mn) + so * __expf(mo - mn); mT = mn;
  }
  const int wv = t >> 6;
  if ((t & 63) == 0) {
    redM[0][wv] = mS; redS[0][wv] = sS;
    redM[1][wv] = mT; redS[1][wv] = sT;
  }
  __syncthreads();   // covers (m,s) publication AND the LDS row writes
  float M0 = redM[0][0], S0 = redS[0][0];
  float M1 = redM[1][0], S1 = redS[1][0];
#pragma unroll
  for (int k = 1; k < 4; ++k) {
    float m2 = redM[0][k], s2 = redS[0][k];
    float mn = fmaxf(M0, m2);
    S0 = S0 * __expf(M0 - mn) + s2 * __expf(m2 - mn); M0 = mn;
    m2 = redM[1][k]; s2 = redS[1][k];
    mn = fmaxf(M1, m2);
    S1 = S1 * __expf(M1 - mn) + s2 * __expf(m2 - mn); M1 = mn;
  }
  const float lseS = M0 + __logf(S0);
  const float lseT = M1 + __logf(S1);

  float acc = 0.f;
  for (int i = t; i < nvec; i += 256) {
    float fs[8], ft[8];
    unpack8(lS[i], fs);
    unpack8(lT[i], ft);
#pragma unroll
    for (int j = 0; j < 8; ++j) {
      const float lq = fs[j] - lseS;
      const float lp = ft[j] - lseT;
      const float q = __expf(lq);
      const float p = __expf(lp);
      const float m = BETA * p + (1.f - BETA) * q;
      const float lm = __logf(m);
      acc += BETA * p * (lp - lm) + (1.f - BETA) * q * (lq - lm);
    }
  }
  acc = blockReduce(acc, red);
  if (t == 0) per_tok[row] = acc;
}

// ---------------------------------------------------------------- finalize
__global__ __launch_bounds__(256) void finalize_kernel(
    const float* __restrict__ per_tok, const int* __restrict__ tgt,
    float* __restrict__ out, int N) {
  __shared__ float redf[4];
  __shared__ int redi[4];
  float s = 0.f;
  int c = 0;
  for (int i = threadIdx.x; i < N; i += 256) {
    if (tgt[i] != IGNORE_INDEX) { s += per_tok[i]; c += 1; }
  }
#pragma unroll
  for (int o = 32; o >= 1; o >>= 1) {
    s += __shfl_xor(s, o, 64);
    c += __shfl_xor(c, o, 64);
  }
  const int w = threadIdx.x >> 6;
  if ((threadIdx.x & 63) == 0) { redf[w] = s; redi[w] = c; }
  __syncthreads();
  if (threadIdx.x == 0) {
    float st = 0.f;
    int ct = 0;
#pragma unroll
    for (int i = 0; i < 4; ++i) { st += redf[i]; ct += redi[i]; }
    out[0] = st / (float)(ct > 0 ? ct : 1);
  }
}

// ---------------------------------------------------------------- launch
extern "C" void kernel_launch(void* const* d_in, const int* in_sizes, int n_in,
                              void* d_out, int out_size, void* d_ws, size_t ws_size,
                              hipStream_t stream) {
  const float* student = (const float*)d_in[0];
  const float* W_s     = (const float*)d_in[1];
  const float* teacher = (const float*)d_in[2];
  const float* W_t     = (const float*)d_in[3];
  const int*   target  = (const int*)d_in[4];

  const int N  = in_sizes[4];            // 2048
  const int Hs = in_sizes[0] / N;        // 2048
  const int Ht = in_sizes[2] / N;        // 4096
  const int V  = in_sizes[1] / Hs;       // 32000

  char* ws = (char*)d_ws;
  size_t off = 0;
  auto alloc = [&](size_t bytes) -> void* {
    void* p = ws + off;
    off += (bytes + 255) & ~(size_t)255;
    return p;
  };
  uint8_t* Sf8  = (uint8_t*)alloc((size_t)N * Hs);
  uint8_t* Wsf8 = (uint8_t*)alloc((size_t)V * Hs);
  uint8_t* Tf8  = (uint8_t*)alloc((size_t)N * Ht);
  uint8_t* Wtf8 = (uint8_t*)alloc((size_t)V * Ht);
  uint16_t* slog = (uint16_t*)alloc((size_t)N * V * 2);
  uint16_t* tlog = (uint16_t*)alloc((size_t)N * V * 2);
  float* per_tok = (float*)alloc((size_t)N * sizeof(float));
  (void)ws_size;  // total ~465 MB

  f32_to_fp8_kernel<<<512, 256, 0, stream>>>(student, Sf8, N * Hs, 1.0f);
  f32_to_fp8_kernel<<<2048, 256, 0, stream>>>(W_s, Wsf8, V * Hs, WSCALE);
  f32_to_fp8_kernel<<<512, 256, 0, stream>>>(teacher, Tf8, N * Ht, 1.0f);
  f32_to_fp8_kernel<<<2048, 256, 0, stream>>>(W_t, Wtf8, V * Ht, WSCALE);

  const int RT = N / 256;   // 8
  const int CT = V / 256;   // 125
  // merged launch: teacher blocks first, student backfills the tail
  gemm_f8_kernel<<<2 * RT * CT, 512, 0, stream>>>(
      Tf8, Wtf8, tlog, Ht, Sf8, Wsf8, slog, Hs, V, RT, CT);

  jsd_rows_kernel<<<N, 256, 0, stream>>>(slog, tlog, per_tok, V);
  finalize_kernel<<<1, 256, 0, stream>>>(per_tok, target, (float*)d_out, N);
}

// Round 12
// 886.334 us; speedup vs baseline: 1.4947x; 1.0410x over previous
//
#include <hip/hip_runtime.h>
#include <hip/hip_bf16.h>
#include <hip/hip_fp8.h>
#include <stdint.h>

#define BETA 0.5f
#define IGNORE_INDEX (-100)
// Weights pre-scaled x64 into fp8 (avoids e4m3 subnormals for sigma~1/64);
// GEMM epilogue multiplies by 1/64.
#define WSCALE 64.0f
#define INV_WSCALE 0.015625f

typedef float f32x4 __attribute__((ext_vector_type(4)));
typedef long longx2 __attribute__((ext_vector_type(2)));

// ---------------------------------------------------------------- converts
__global__ __launch_bounds__(256) void f32_to_fp8_kernel(
    const float* __restrict__ in, uint8_t* __restrict__ out, int n, float scale) {
  int i = (blockIdx.x * blockDim.x + threadIdx.x) * 8;
  const int stride = gridDim.x * blockDim.x * 8;
  for (; i < n; i += stride) {
    float4 v0 = *reinterpret_cast<const float4*>(in + i);
    float4 v1 = *reinterpret_cast<const float4*>(in + i + 4);
    const float f[8] = {v0.x, v0.y, v0.z, v0.w, v1.x, v1.y, v1.z, v1.w};
    union { uint8_t b[8]; uint2 u; } o;
#pragma unroll
    for (int j = 0; j < 8; ++j) {
      __hip_fp8_e4m3 h(f[j] * scale);
      o.b[j] = h.__x;
    }
    *reinterpret_cast<uint2*>(out + i) = o.u;
  }
}

// ---------------------------------------------------------------- GEMM (NT)
// C[n][v] = (1/64)*sum_k A[n][k]*B[v][k], A/B fp8 e4m3, C bf16.
// 256x256 tile, BK=64, 8 waves (2Mx4N), r7 schedule (barrier-free tile
// body, 1 boundary barrier, counted vmcnt, setprio, XCD swizzle).
// K-PERMUTATION TRICK: GEMM is invariant under a shared k-permutation of
// A and B, so each lane does ONE ds_read_b128 of 16-B quad kg (octets
// 2kg,2kg+1) and feeds low 8 B to MFMA slot s0, high 8 B to s1.  The two
// MFMAs' k-sets partition 0..63.  This (a) halves the LDS read count
// (12 b128/wave/tile), (b) makes the swizzle granule 16 B = the gload_lds
// granule: phys_quad = logical ^ ((row>>2)&3), conflict-free (16 distinct
// 16-B units per 16-lane pass, same structure as the 0-conflict r7 layout).
// LDS: 2 buf x (A 16K | B 16K) = 64 KiB.
// Merged launch: blocks [0,half) = teacher, [half,2*half) = student.

__global__ __launch_bounds__(512, 2) void gemm_f8q_kernel(
    const uint8_t* __restrict__ At, const uint8_t* __restrict__ Bt,
    uint16_t* __restrict__ Ct, int Kt,
    const uint8_t* __restrict__ As_, const uint8_t* __restrict__ Bs_,
    uint16_t* __restrict__ Cs, int Ks,
    int V, int RT, int CT) {
  __shared__ __align__(16) uint8_t lds[65536];

  const int half = RT * CT;
  const uint8_t *A, *B;
  uint16_t* C;
  int K, bidx = blockIdx.x;
  if (bidx < half) { A = At; B = Bt; C = Ct; K = Kt; }
  else             { A = As_; B = Bs_; C = Cs; K = Ks; bidx -= half; }

  int L = ((half & 7) == 0) ? ((bidx & 7) * (half >> 3) + (bidx >> 3)) : bidx;
  const int rt = L % RT;
  const int ct = L / RT;
  const int row0 = rt * 256;
  const int col0 = ct * 256;

  const int i  = threadIdx.x;      // 0..511
  const int w  = i >> 6;
  const int l  = i & 63;
  const int wl = l & 15;
  const int kg = l >> 4;
  const int wr = w >> 2;           // wave row 0..1 (128 out rows)
  const int wc = w & 3;            // wave col 0..3 (64 out cols)

  const int nT = K >> 6;           // BK = 64

  // ---- staging: thread i -> quad (row rg, phys pq) sources logical quad
  // pq ^ ((rg>>2)&3); rows rg and rg+128 share the XOR term.
  const int rg = i >> 2;           // 0..127
  const int pq = i & 3;
  const int qlog = pq ^ ((rg >> 2) & 3);
  const uint8_t* aSrc = A + (size_t)(row0 + rg) * K + qlog * 16;
  const uint8_t* bSrc = B + (size_t)(col0 + rg) * K + qlog * 16;
  uint8_t* ldsu = lds;

#define GL(srcp, dstp)                                                     \
  __builtin_amdgcn_global_load_lds(                                        \
      (const __attribute__((address_space(1))) void*)(srcp),               \
      (__attribute__((address_space(3))) void*)(dstp), 16, 0, 0)

#define STAGE_A(TT)                                                        \
  do {                                                                     \
    const uint8_t* _s = aSrc + (size_t)(TT) * 64;                          \
    uint8_t* _d = ldsu + (((TT) & 1) * 32768) + i * 16;                    \
    GL(_s, _d); GL(_s + (size_t)128 * K, _d + 8192);                       \
  } while (0)

#define STAGE_B(TT)                                                        \
  do {                                                                     \
    const uint8_t* _s = bSrc + (size_t)(TT) * 64;                          \
    uint8_t* _d = ldsu + (((TT) & 1) * 32768) + 16384 + i * 16;            \
    GL(_s, _d); GL(_s + (size_t)128 * K, _d + 8192);                       \
  } while (0)

  // ---- ds_read_b128 byte offsets: row r, phys quad = kg ^ ((wl>>2)&3)
  // ((r>>2)&3 == (wl>>2)&3 since all row bases are multiples of 16).
  int offA[8], offB[4];
  const int qsw = (kg ^ (wl >> 2)) * 16;
#pragma unroll
  for (int m = 0; m < 8; ++m) {
    const int r = wr * 128 + m * 16 + wl;
    offA[m] = r * 64 + qsw;
  }
#pragma unroll
  for (int n = 0; n < 4; ++n) {
    const int r = wc * 64 + n * 16 + wl;
    offB[n] = 16384 + r * 64 + qsw;
  }

  f32x4 acc[8][4] = {};
  longx2 af[4], ag[4], bf[4];

  // ---- prologue: stage A(0)+B(0)+B(1); wait tile0 (vmcnt 2)
  STAGE_A(0); STAGE_B(0);
  if (nT > 1) {
    STAGE_B(1);
    asm volatile("s_waitcnt vmcnt(2)" ::: "memory");
  } else {
    asm volatile("s_waitcnt vmcnt(0)" ::: "memory");
  }
  __builtin_amdgcn_s_barrier();
  __builtin_amdgcn_sched_barrier(0);

  for (int T = 0; T < nT; ++T) {
    const uint8_t* bb = lds + (T & 1) * 32768;
    const bool stg1 = (T + 1) < nT;
    const bool stg2 = (T + 2) < nT;

    // chunk 1: read A m0..3 + B n0..3 (8 b128); stage A(T+1); MFMA m0..3 s0
#pragma unroll
    for (int m = 0; m < 4; ++m)
      af[m] = *reinterpret_cast<const longx2*>(bb + offA[m]);
#pragma unroll
    for (int n = 0; n < 4; ++n)
      bf[n] = *reinterpret_cast<const longx2*>(bb + offB[n]);
    if (stg1) STAGE_A(T + 1);
    __builtin_amdgcn_s_setprio(1);
#pragma unroll
    for (int m = 0; m < 4; ++m)
#pragma unroll
      for (int n = 0; n < 4; ++n)
        acc[m][n] = __builtin_amdgcn_mfma_f32_16x16x32_fp8_fp8(
            af[m][0], bf[n][0], acc[m][n], 0, 0, 0);
    __builtin_amdgcn_s_setprio(0);

    // chunk 2: read A m4..7 (4 b128); MFMA m4..7 s0
#pragma unroll
    for (int m = 0; m < 4; ++m)
      ag[m] = *reinterpret_cast<const longx2*>(bb + offA[4 + m]);
    __builtin_amdgcn_s_setprio(1);
#pragma unroll
    for (int m = 0; m < 4; ++m)
#pragma unroll
      for (int n = 0; n < 4; ++n)
        acc[4 + m][n] = __builtin_amdgcn_mfma_f32_16x16x32_fp8_fp8(
            ag[m][0], bf[n][0], acc[4 + m][n], 0, 0, 0);
    __builtin_amdgcn_s_setprio(0);

    // chunk 3: stage B(T+2); MFMA m0..3 s1 (high halves, no reads)
    if (stg2) STAGE_B(T + 2);
    __builtin_amdgcn_s_setprio(1);
#pragma unroll
    for (int m = 0; m < 4; ++m)
#pragma unroll
      for (int n = 0; n < 4; ++n)
        acc[m][n] = __builtin_amdgcn_mfma_f32_16x16x32_fp8_fp8(
            af[m][1], bf[n][1], acc[m][n], 0, 0, 0);
    __builtin_amdgcn_s_setprio(0);

    // chunk 4: MFMA m4..7 s1
    __builtin_amdgcn_s_setprio(1);
#pragma unroll
    for (int m = 0; m < 4; ++m)
#pragma unroll
      for (int n = 0; n < 4; ++n)
        acc[4 + m][n] = __builtin_amdgcn_mfma_f32_16x16x32_fp8_fp8(
            ag[m][1], bf[n][1], acc[4 + m][n], 0, 0, 0);
    __builtin_amdgcn_s_setprio(0);

    // boundary: counted vmcnt (A(T+1) done, B(T+2) in flight), barrier
    if (stg2) {
      asm volatile("s_waitcnt vmcnt(2)" ::: "memory");
    } else {
      asm volatile("s_waitcnt vmcnt(0)" ::: "memory");
    }
    __builtin_amdgcn_s_barrier();
    __builtin_amdgcn_sched_barrier(0);
  }

  // epilogue: C/D layout col=lane&15, row=(lane>>4)*4+reg; x 1/64 (W scale)
#pragma unroll
  for (int mg = 0; mg < 8; ++mg)
#pragma unroll
    for (int ng = 0; ng < 4; ++ng)
#pragma unroll
      for (int r = 0; r < 4; ++r) {
        const int row = row0 + wr * 128 + mg * 16 + kg * 4 + r;
        const int col = col0 + wc * 64 + ng * 16 + wl;
        __hip_bfloat16 bv = __float2bfloat16(acc[mg][ng][r] * INV_WSCALE);
        C[(size_t)row * V + col] = *reinterpret_cast<const uint16_t*>(&bv);
      }
#undef STAGE_A
#undef STAGE_B
#undef GL
}

// ---------------------------------------------------------------- JSD rows
__device__ __forceinline__ void unpack8(uint4 v, float* f) {
  uint32_t w[4] = {v.x, v.y, v.z, v.w};
#pragma unroll
  for (int j = 0; j < 4; ++j) {
    union { uint32_t u; float x; } lo, hi;
    lo.u = (w[j] & 0xffffu) << 16;
    hi.u = w[j] & 0xffff0000u;
    f[2 * j] = lo.x;
    f[2 * j + 1] = hi.x;
  }
}

__device__ __forceinline__ float blockReduce(float v, float* sh) {
#pragma unroll
  for (int o = 32; o >= 1; o >>= 1) v += __shfl_xor(v, o, 64);
  const int w = threadIdx.x >> 6;
  __syncthreads();
  if ((threadIdx.x & 63) == 0) sh[w] = v;
  __syncthreads();
  float r = sh[0];
#pragma unroll
  for (int i = 1; i < 4; ++i) r += sh[i];
  return r;
}

// online-LSE load pass (1 global sweep, fused max+sum) + 1 LDS JSD pass.
__global__ __launch_bounds__(256) void jsd_rows_kernel(
    const uint16_t* __restrict__ SL, const uint16_t* __restrict__ TL,
    float* __restrict__ per_tok, int V) {
  __shared__ __align__(16) uint16_t rowS[32000];
  __shared__ __align__(16) uint16_t rowT[32000];
  __shared__ float redM[2][4], redS[2][4], red[4];

  const int t = threadIdx.x;
  const int row = blockIdx.x;
  const uint4* gS = reinterpret_cast<const uint4*>(SL + (size_t)row * V);
  const uint4* gT = reinterpret_cast<const uint4*>(TL + (size_t)row * V);
  uint4* lS = reinterpret_cast<uint4*>(rowS);
  uint4* lT = reinterpret_cast<uint4*>(rowT);
  const int nvec = V >> 3;  // 4000

  float mS = -3.0e38f, sS = 0.f, mT = -3.0e38f, sT = 0.f;
  for (int i = t; i < nvec; i += 256) {
    uint4 vs = gS[i], vt = gT[i];
    lS[i] = vs; lT[i] = vt;
    float fs[8], ft[8];
    unpack8(vs, fs);
    unpack8(vt, ft);
    float vmS = fs[0], vmT = ft[0];
#pragma unroll
    for (int j = 1; j < 8; ++j) { vmS = fmaxf(vmS, fs[j]); vmT = fmaxf(vmT, ft[j]); }
    if (vmS > mS) { sS *= __expf(mS - vmS); mS = vmS; }
    if (vmT > mT) { sT *= __expf(mT - vmT); mT = vmT; }
#pragma unroll
    for (int j = 0; j < 8; ++j) { sS += __expf(fs[j] - mS); sT += __expf(ft[j] - mT); }
  }

#pragma unroll
  for (int o = 32; o >= 1; o >>= 1) {
    float mo = __shfl_xor(mS, o, 64), so = __shfl_xor(sS, o, 64);
    float mn = fmaxf(mS, mo);
    sS = sS * __expf(mS - mn) + so * __expf(mo - mn); mS = mn;
    mo = __shfl_xor(mT, o, 64); so = __shfl_xor(sT, o, 64);
    mn = fmaxf(mT, mo);
    sT = sT * __expf(mT - mn) + so * __expf(mo - mn); mT = mn;
  }
  const int wv = t >> 6;
  if ((t & 63) == 0) {
    redM[0][wv] = mS; redS[0][wv] = sS;
    redM[1][wv] = mT; redS[1][wv] = sT;
  }
  __syncthreads();   // covers (m,s) publication AND the LDS row writes
  float M0 = redM[0][0], S0 = redS[0][0];
  float M1 = redM[1][0], S1 = redS[1][0];
#pragma unroll
  for (int k = 1; k < 4; ++k) {
    float m2 = redM[0][k], s2 = redS[0][k];
    float mn = fmaxf(M0, m2);
    S0 = S0 * __expf(M0 - mn) + s2 * __expf(m2 - mn); M0 = mn;
    m2 = redM[1][k]; s2 = redS[1][k];
    mn = fmaxf(M1, m2);
    S1 = S1 * __expf(M1 - mn) + s2 * __expf(m2 - mn); M1 = mn;
  }
  const float lseS = M0 + __logf(S0);
  const float lseT = M1 + __logf(S1);

  float acc = 0.f;
  for (int i = t; i < nvec; i += 256) {
    float fs[8], ft[8];
    unpack8(lS[i], fs);
    unpack8(lT[i], ft);
#pragma unroll
    for (int j = 0; j < 8; ++j) {
      const float lq = fs[j] - lseS;
      const float lp = ft[j] - lseT;
      const float q = __expf(lq);
      const float p = __expf(lp);
      const float m = BETA * p + (1.f - BETA) * q;
      const float lm = __logf(m);
      acc += BETA * p * (lp - lm) + (1.f - BETA) * q * (lq - lm);
    }
  }
  acc = blockReduce(acc, red);
  if (t == 0) per_tok[row] = acc;
}

// ---------------------------------------------------------------- finalize
__global__ __launch_bounds__(256) void finalize_kernel(
    const float* __restrict__ per_tok, const int* __restrict__ tgt,
    float* __restrict__ out, int N) {
  __shared__ float redf[4];
  __shared__ int redi[4];
  float s = 0.f;
  int c = 0;
  for (int i = threadIdx.x; i < N; i += 256) {
    if (tgt[i] != IGNORE_INDEX) { s += per_tok[i]; c += 1; }
  }
#pragma unroll
  for (int o = 32; o >= 1; o >>= 1) {
    s += __shfl_xor(s, o, 64);
    c += __shfl_xor(c, o, 64);
  }
  const int w = threadIdx.x >> 6;
  if ((threadIdx.x & 63) == 0) { redf[w] = s; redi[w] = c; }
  __syncthreads();
  if (threadIdx.x == 0) {
    float st = 0.f;
    int ct = 0;
#pragma unroll
    for (int i = 0; i < 4; ++i) { st += redf[i]; ct += redi[i]; }
    out[0] = st / (float)(ct > 0 ? ct : 1);
  }
}

// ---------------------------------------------------------------- launch
extern "C" void kernel_launch(void* const* d_in, const int* in_sizes, int n_in,
                              void* d_out, int out_size, void* d_ws, size_t ws_size,
                              hipStream_t stream) {
  const float* student = (const float*)d_in[0];
  const float* W_s     = (const float*)d_in[1];
  const float* teacher = (const float*)d_in[2];
  const float* W_t     = (const float*)d_in[3];
  const int*   target  = (const int*)d_in[4];

  const int N  = in_sizes[4];            // 2048
  const int Hs = in_sizes[0] / N;        // 2048
  const int Ht = in_sizes[2] / N;        // 4096
  const int V  = in_sizes[1] / Hs;       // 32000

  char* ws = (char*)d_ws;
  size_t off = 0;
  auto alloc = [&](size_t bytes) -> void* {
    void* p = ws + off;
    off += (bytes + 255) & ~(size_t)255;
    return p;
  };
  uint8_t* Sf8  = (uint8_t*)alloc((size_t)N * Hs);
  uint8_t* Wsf8 = (uint8_t*)alloc((size_t)V * Hs);
  uint8_t* Tf8  = (uint8_t*)alloc((size_t)N * Ht);
  uint8_t* Wtf8 = (uint8_t*)alloc((size_t)V * Ht);
  uint16_t* slog = (uint16_t*)alloc((size_t)N * V * 2);
  uint16_t* tlog = (uint16_t*)alloc((size_t)N * V * 2);
  float* per_tok = (float*)alloc((size_t)N * sizeof(float));
  (void)ws_size;  // total ~465 MB

  f32_to_fp8_kernel<<<512, 256, 0, stream>>>(student, Sf8, N * Hs, 1.0f);
  f32_to_fp8_kernel<<<2048, 256, 0, stream>>>(W_s, Wsf8, V * Hs, WSCALE);
  f32_to_fp8_kernel<<<512, 256, 0, stream>>>(teacher, Tf8, N * Ht, 1.0f);
  f32_to_fp8_kernel<<<2048, 256, 0, stream>>>(W_t, Wtf8, V * Ht, WSCALE);

  const int RT = N / 256;   // 8
  const int CT = V / 256;   // 125
  // merged launch: teacher blocks first, student backfills the tail
  gemm_f8q_kernel<<<2 * RT * CT, 512, 0, stream>>>(
      Tf8, Wtf8, tlog, Ht, Sf8, Wsf8, slog, Hs, V, RT, CT);

  jsd_rows_kernel<<<N, 256, 0, stream>>>(slog, tlog, per_tok, V);
  finalize_kernel<<<1, 256, 0, stream>>>(per_tok, target, (float*)d_out, N);
}

// Round 13
// 874.117 us; speedup vs baseline: 1.5155x; 1.0140x over previous
//
#include <hip/hip_runtime.h>
#include <hip/hip_bf16.h>
#include <hip/hip_fp8.h>
#include <stdint.h>

#define BETA 0.5f
#define IGNORE_INDEX (-100)
// Weights pre-scaled x64 into fp8 (avoids e4m3 subnormals for sigma~1/64);
// GEMM epilogue multiplies by 1/64.
#define WSCALE 64.0f
#define INV_WSCALE 0.015625f

typedef float f32x4 __attribute__((ext_vector_type(4)));
typedef long longx2 __attribute__((ext_vector_type(2)));

// ---------------------------------------------------------------- converts
__global__ __launch_bounds__(256) void f32_to_fp8_kernel(
    const float* __restrict__ in, uint8_t* __restrict__ out, int n, float scale) {
  int i = (blockIdx.x * blockDim.x + threadIdx.x) * 8;
  const int stride = gridDim.x * blockDim.x * 8;
  for (; i < n; i += stride) {
    float4 v0 = *reinterpret_cast<const float4*>(in + i);
    float4 v1 = *reinterpret_cast<const float4*>(in + i + 4);
    const float f[8] = {v0.x, v0.y, v0.z, v0.w, v1.x, v1.y, v1.z, v1.w};
    union { uint8_t b[8]; uint2 u; } o;
#pragma unroll
    for (int j = 0; j < 8; ++j) {
      __hip_fp8_e4m3 h(f[j] * scale);
      o.b[j] = h.__x;
    }
    *reinterpret_cast<uint2*>(out + i) = o.u;
  }
}

// ---------------------------------------------------------------- GEMM (NT)
// C[n][v] = (1/64)*sum_k A[n][k]*B[v][k], A/B fp8 e4m3, C bf16.
// 256x256 tile, BK=64, 8 waves (2Mx4N), r7 schedule (barrier-free tile
// body, 1 boundary barrier, counted vmcnt, setprio, XCD swizzle).
// K-permutation trick (r12): one ds_read_b128 of 16-B quad per lane feeds
// MFMA slots s0 (low 8 B) and s1 (high 8 B); A and B share the k-perm.
// SWIZZLE FIX (r13): phys_quad = kg ^ ((row>>1)&3).  LDS serves b128 in
// 8-consecutive-lane groups needing 8 distinct 16-B units in the 128-B
// bank window; with 64-B rows, rows 2 apart fold onto the same banks, so
// the XOR must be a bijection over (row>>1)&3 within each group --
// (row>>2) (r12) repeated 2 lanes apart = 4.0 extra cyc/read; (row>>1)
// gives even lanes 0,2,4,6 -> units 0..3 of the even half-window, odd
// lanes likewise.  Matches r7-bf16's 0-conflict structure.
// LDS: 2 buf x (A 16K | B 16K) = 64 KiB.
// Merged launch: blocks [0,half) = teacher, [half,2*half) = student.

__global__ __launch_bounds__(512, 2) void gemm_f8q_kernel(
    const uint8_t* __restrict__ At, const uint8_t* __restrict__ Bt,
    uint16_t* __restrict__ Ct, int Kt,
    const uint8_t* __restrict__ As_, const uint8_t* __restrict__ Bs_,
    uint16_t* __restrict__ Cs, int Ks,
    int V, int RT, int CT) {
  __shared__ __align__(16) uint8_t lds[65536];

  const int half = RT * CT;
  const uint8_t *A, *B;
  uint16_t* C;
  int K, bidx = blockIdx.x;
  if (bidx < half) { A = At; B = Bt; C = Ct; K = Kt; }
  else             { A = As_; B = Bs_; C = Cs; K = Ks; bidx -= half; }

  int L = ((half & 7) == 0) ? ((bidx & 7) * (half >> 3) + (bidx >> 3)) : bidx;
  const int rt = L % RT;
  const int ct = L / RT;
  const int row0 = rt * 256;
  const int col0 = ct * 256;

  const int i  = threadIdx.x;      // 0..511
  const int w  = i >> 6;
  const int l  = i & 63;
  const int wl = l & 15;
  const int kg = l >> 4;
  const int wr = w >> 2;           // wave row 0..1 (128 out rows)
  const int wc = w & 3;            // wave col 0..3 (64 out cols)

  const int nT = K >> 6;           // BK = 64

  // ---- staging: thread i -> quad (row rg, phys pq) sources logical quad
  // pq ^ ((rg>>1)&3); rows rg and rg+128 share the XOR term (64 = 0 mod 4).
  const int rg = i >> 2;           // 0..127
  const int pq = i & 3;
  const int qlog = pq ^ ((rg >> 1) & 3);
  const uint8_t* aSrc = A + (size_t)(row0 + rg) * K + qlog * 16;
  const uint8_t* bSrc = B + (size_t)(col0 + rg) * K + qlog * 16;
  uint8_t* ldsu = lds;

#define GL(srcp, dstp)                                                     \
  __builtin_amdgcn_global_load_lds(                                        \
      (const __attribute__((address_space(1))) void*)(srcp),               \
      (__attribute__((address_space(3))) void*)(dstp), 16, 0, 0)

#define STAGE_A(TT)                                                        \
  do {                                                                     \
    const uint8_t* _s = aSrc + (size_t)(TT) * 64;                          \
    uint8_t* _d = ldsu + (((TT) & 1) * 32768) + i * 16;                    \
    GL(_s, _d); GL(_s + (size_t)128 * K, _d + 8192);                       \
  } while (0)

#define STAGE_B(TT)                                                        \
  do {                                                                     \
    const uint8_t* _s = bSrc + (size_t)(TT) * 64;                          \
    uint8_t* _d = ldsu + (((TT) & 1) * 32768) + 16384 + i * 16;            \
    GL(_s, _d); GL(_s + (size_t)128 * K, _d + 8192);                       \
  } while (0)

  // ---- ds_read_b128 byte offsets: row r, phys quad = kg ^ ((r>>1)&3);
  // row bases are multiples of 16 so (r>>1)&3 == (wl>>1)&3.
  int offA[8], offB[4];
  const int qsw = (kg ^ ((wl >> 1) & 3)) * 16;
#pragma unroll
  for (int m = 0; m < 8; ++m) {
    const int r = wr * 128 + m * 16 + wl;
    offA[m] = r * 64 + qsw;
  }
#pragma unroll
  for (int n = 0; n < 4; ++n) {
    const int r = wc * 64 + n * 16 + wl;
    offB[n] = 16384 + r * 64 + qsw;
  }

  f32x4 acc[8][4] = {};
  longx2 af[4], ag[4], bf[4];

  // ---- prologue: stage A(0)+B(0)+B(1); wait tile0 (vmcnt 2)
  STAGE_A(0); STAGE_B(0);
  if (nT > 1) {
    STAGE_B(1);
    asm volatile("s_waitcnt vmcnt(2)" ::: "memory");
  } else {
    asm volatile("s_waitcnt vmcnt(0)" ::: "memory");
  }
  __builtin_amdgcn_s_barrier();
  __builtin_amdgcn_sched_barrier(0);

  for (int T = 0; T < nT; ++T) {
    const uint8_t* bb = lds + (T & 1) * 32768;
    const bool stg1 = (T + 1) < nT;
    const bool stg2 = (T + 2) < nT;

    // chunk 1: read A m0..3 + B n0..3 (8 b128); stage A(T+1); MFMA m0..3 s0
#pragma unroll
    for (int m = 0; m < 4; ++m)
      af[m] = *reinterpret_cast<const longx2*>(bb + offA[m]);
#pragma unroll
    for (int n = 0; n < 4; ++n)
      bf[n] = *reinterpret_cast<const longx2*>(bb + offB[n]);
    if (stg1) STAGE_A(T + 1);
    __builtin_amdgcn_s_setprio(1);
#pragma unroll
    for (int m = 0; m < 4; ++m)
#pragma unroll
      for (int n = 0; n < 4; ++n)
        acc[m][n] = __builtin_amdgcn_mfma_f32_16x16x32_fp8_fp8(
            af[m][0], bf[n][0], acc[m][n], 0, 0, 0);
    __builtin_amdgcn_s_setprio(0);

    // chunk 2: read A m4..7 (4 b128); MFMA m4..7 s0
#pragma unroll
    for (int m = 0; m < 4; ++m)
      ag[m] = *reinterpret_cast<const longx2*>(bb + offA[4 + m]);
    __builtin_amdgcn_s_setprio(1);
#pragma unroll
    for (int m = 0; m < 4; ++m)
#pragma unroll
      for (int n = 0; n < 4; ++n)
        acc[4 + m][n] = __builtin_amdgcn_mfma_f32_16x16x32_fp8_fp8(
            ag[m][0], bf[n][0], acc[4 + m][n], 0, 0, 0);
    __builtin_amdgcn_s_setprio(0);

    // chunk 3: stage B(T+2); MFMA m0..3 s1 (high halves, no reads)
    if (stg2) STAGE_B(T + 2);
    __builtin_amdgcn_s_setprio(1);
#pragma unroll
    for (int m = 0; m < 4; ++m)
#pragma unroll
      for (int n = 0; n < 4; ++n)
        acc[m][n] = __builtin_amdgcn_mfma_f32_16x16x32_fp8_fp8(
            af[m][1], bf[n][1], acc[m][n], 0, 0, 0);
    __builtin_amdgcn_s_setprio(0);

    // chunk 4: MFMA m4..7 s1
    __builtin_amdgcn_s_setprio(1);
#pragma unroll
    for (int m = 0; m < 4; ++m)
#pragma unroll
      for (int n = 0; n < 4; ++n)
        acc[4 + m][n] = __builtin_amdgcn_mfma_f32_16x16x32_fp8_fp8(
            ag[m][1], bf[n][1], acc[4 + m][n], 0, 0, 0);
    __builtin_amdgcn_s_setprio(0);

    // boundary: counted vmcnt (A(T+1) done, B(T+2) in flight), barrier
    if (stg2) {
      asm volatile("s_waitcnt vmcnt(2)" ::: "memory");
    } else {
      asm volatile("s_waitcnt vmcnt(0)" ::: "memory");
    }
    __builtin_amdgcn_s_barrier();
    __builtin_amdgcn_sched_barrier(0);
  }

  // epilogue: C/D layout col=lane&15, row=(lane>>4)*4+reg; x 1/64 (W scale)
#pragma unroll
  for (int mg = 0; mg < 8; ++mg)
#pragma unroll
    for (int ng = 0; ng < 4; ++ng)
#pragma unroll
      for (int r = 0; r < 4; ++r) {
        const int row = row0 + wr * 128 + mg * 16 + kg * 4 + r;
        const int col = col0 + wc * 64 + ng * 16 + wl;
        __hip_bfloat16 bv = __float2bfloat16(acc[mg][ng][r] * INV_WSCALE);
        C[(size_t)row * V + col] = *reinterpret_cast<const uint16_t*>(&bv);
      }
#undef STAGE_A
#undef STAGE_B
#undef GL
}

// ---------------------------------------------------------------- JSD rows
__device__ __forceinline__ void unpack8(uint4 v, float* f) {
  uint32_t w[4] = {v.x, v.y, v.z, v.w};
#pragma unroll
  for (int j = 0; j < 4; ++j) {
    union { uint32_t u; float x; } lo, hi;
    lo.u = (w[j] & 0xffffu) << 16;
    hi.u = w[j] & 0xffff0000u;
    f[2 * j] = lo.x;
    f[2 * j + 1] = hi.x;
  }
}

__device__ __forceinline__ float blockReduce(float v, float* sh) {
#pragma unroll
  for (int o = 32; o >= 1; o >>= 1) v += __shfl_xor(v, o, 64);
  const int w = threadIdx.x >> 6;
  __syncthreads();
  if ((threadIdx.x & 63) == 0) sh[w] = v;
  __syncthreads();
  float r = sh[0];
#pragma unroll
  for (int i = 1; i < 4; ++i) r += sh[i];
  return r;
}

// online-LSE load pass (1 global sweep, fused max+sum) + 1 LDS JSD pass.
__global__ __launch_bounds__(256) void jsd_rows_kernel(
    const uint16_t* __restrict__ SL, const uint16_t* __restrict__ TL,
    float* __restrict__ per_tok, int V) {
  __shared__ __align__(16) uint16_t rowS[32000];
  __shared__ __align__(16) uint16_t rowT[32000];
  __shared__ float redM[2][4], redS[2][4], red[4];

  const int t = threadIdx.x;
  const int row = blockIdx.x;
  const uint4* gS = reinterpret_cast<const uint4*>(SL + (size_t)row * V);
  const uint4* gT = reinterpret_cast<const uint4*>(TL + (size_t)row * V);
  uint4* lS = reinterpret_cast<uint4*>(rowS);
  uint4* lT = reinterpret_cast<uint4*>(rowT);
  const int nvec = V >> 3;  // 4000

  float mS = -3.0e38f, sS = 0.f, mT = -3.0e38f, sT = 0.f;
  for (int i = t; i < nvec; i += 256) {
    uint4 vs = gS[i], vt = gT[i];
    lS[i] = vs; lT[i] = vt;
    float fs[8], ft[8];
    unpack8(vs, fs);
    unpack8(vt, ft);
    float vmS = fs[0], vmT = ft[0];
#pragma unroll
    for (int j = 1; j < 8; ++j) { vmS = fmaxf(vmS, fs[j]); vmT = fmaxf(vmT, ft[j]); }
    if (vmS > mS) { sS *= __expf(mS - vmS); mS = vmS; }
    if (vmT > mT) { sT *= __expf(mT - vmT); mT = vmT; }
#pragma unroll
    for (int j = 0; j < 8; ++j) { sS += __expf(fs[j] - mS); sT += __expf(ft[j] - mT); }
  }

#pragma unroll
  for (int o = 32; o >= 1; o >>= 1) {
    float mo = __shfl_xor(mS, o, 64), so = __shfl_xor(sS, o, 64);
    float mn = fmaxf(mS, mo);
    sS = sS * __expf(mS - mn) + so * __expf(mo - mn); mS = mn;
    mo = __shfl_xor(mT, o, 64); so = __shfl_xor(sT, o, 64);
    mn = fmaxf(mT, mo);
    sT = sT * __expf(mT - mn) + so * __expf(mo - mn); mT = mn;
  }
  const int wv = t >> 6;
  if ((t & 63) == 0) {
    redM[0][wv] = mS; redS[0][wv] = sS;
    redM[1][wv] = mT; redS[1][wv] = sT;
  }
  __syncthreads();   // covers (m,s) publication AND the LDS row writes
  float M0 = redM[0][0], S0 = redS[0][0];
  float M1 = redM[1][0], S1 = redS[1][0];
#pragma unroll
  for (int k = 1; k < 4; ++k) {
    float m2 = redM[0][k], s2 = redS[0][k];
    float mn = fmaxf(M0, m2);
    S0 = S0 * __expf(M0 - mn) + s2 * __expf(m2 - mn); M0 = mn;
    m2 = redM[1][k]; s2 = redS[1][k];
    mn = fmaxf(M1, m2);
    S1 = S1 * __expf(M1 - mn) + s2 * __expf(m2 - mn); M1 = mn;
  }
  const float lseS = M0 + __logf(S0);
  const float lseT = M1 + __logf(S1);

  float acc = 0.f;
  for (int i = t; i < nvec; i += 256) {
    float fs[8], ft[8];
    unpack8(lS[i], fs);
    unpack8(lT[i], ft);
#pragma unroll
    for (int j = 0; j < 8; ++j) {
      const float lq = fs[j] - lseS;
      const float lp = ft[j] - lseT;
      const float q = __expf(lq);
      const float p = __expf(lp);
      const float m = BETA * p + (1.f - BETA) * q;
      const float lm = __logf(m);
      acc += BETA * p * (lp - lm) + (1.f - BETA) * q * (lq - lm);
    }
  }
  acc = blockReduce(acc, red);
  if (t == 0) per_tok[row] = acc;
}

// ---------------------------------------------------------------- finalize
__global__ __launch_bounds__(256) void finalize_kernel(
    const float* __restrict__ per_tok, const int* __restrict__ tgt,
    float* __restrict__ out, int N) {
  __shared__ float redf[4];
  __shared__ int redi[4];
  float s = 0.f;
  int c = 0;
  for (int i = threadIdx.x; i < N; i += 256) {
    if (tgt[i] != IGNORE_INDEX) { s += per_tok[i]; c += 1; }
  }
#pragma unroll
  for (int o = 32; o >= 1; o >>= 1) {
    s += __shfl_xor(s, o, 64);
    c += __shfl_xor(c, o, 64);
  }
  const int w = threadIdx.x >> 6;
  if ((threadIdx.x & 63) == 0) { redf[w] = s; redi[w] = c; }
  __syncthreads();
  if (threadIdx.x == 0) {
    float st = 0.f;
    int ct = 0;
#pragma unroll
    for (int i = 0; i < 4; ++i) { st += redf[i]; ct += redi[i]; }
    out[0] = st / (float)(ct > 0 ? ct : 1);
  }
}

// ---------------------------------------------------------------- launch
extern "C" void kernel_launch(void* const* d_in, const int* in_sizes, int n_in,
                              void* d_out, int out_size, void* d_ws, size_t ws_size,
                              hipStream_t stream) {
  const float* student = (const float*)d_in[0];
  const float* W_s     = (const float*)d_in[1];
  const float* teacher = (const float*)d_in[2];
  const float* W_t     = (const float*)d_in[3];
  const int*   target  = (const int*)d_in[4];

  const int N  = in_sizes[4];            // 2048
  const int Hs = in_sizes[0] / N;        // 2048
  const int Ht = in_sizes[2] / N;        // 4096
  const int V  = in_sizes[1] / Hs;       // 32000

  char* ws = (char*)d_ws;
  size_t off = 0;
  auto alloc = [&](size_t bytes) -> void* {
    void* p = ws + off;
    off += (bytes + 255) & ~(size_t)255;
    return p;
  };
  uint8_t* Sf8  = (uint8_t*)alloc((size_t)N * Hs);
  uint8_t* Wsf8 = (uint8_t*)alloc((size_t)V * Hs);
  uint8_t* Tf8  = (uint8_t*)alloc((size_t)N * Ht);
  uint8_t* Wtf8 = (uint8_t*)alloc((size_t)V * Ht);
  uint16_t* slog = (uint16_t*)alloc((size_t)N * V * 2);
  uint16_t* tlog = (uint16_t*)alloc((size_t)N * V * 2);
  float* per_tok = (float*)alloc((size_t)N * sizeof(float));
  (void)ws_size;  // total ~465 MB

  f32_to_fp8_kernel<<<512, 256, 0, stream>>>(student, Sf8, N * Hs, 1.0f);
  f32_to_fp8_kernel<<<2048, 256, 0, stream>>>(W_s, Wsf8, V * Hs, WSCALE);
  f32_to_fp8_kernel<<<512, 256, 0, stream>>>(teacher, Tf8, N * Ht, 1.0f);
  f32_to_fp8_kernel<<<2048, 256, 0, stream>>>(W_t, Wtf8, V * Ht, WSCALE);

  const int RT = N / 256;   // 8
  const int CT = V / 256;   // 125
  // merged launch: teacher blocks first, student backfills the tail
  gemm_f8q_kernel<<<2 * RT * CT, 512, 0, stream>>>(
      Tf8, Wtf8, tlog, Ht, Sf8, Wsf8, slog, Hs, V, RT, CT);

  jsd_rows_kernel<<<N, 256, 0, stream>>>(slog, tlog, per_tok, V);
  finalize_kernel<<<1, 256, 0, stream>>>(per_tok, target, (float*)d_out, N);
}